// Round 2
// baseline (398.234 us; speedup 1.0000x reference)
//
#include <hip/hip_runtime.h>
#include <cstdint>
#include <cstddef>

// Problem constants
#define BB 4
#define TT 2048
#define DD 1024
#define HH 8
#define DH 64
#define EE 5
#define MM (BB*TT)          // 8192 rows
#define PLD 1344            // proj leading dim (q 512 | k 512 | xv 320)
#define NWT 1408            // padded N for MFMA proj (11 * 128)

typedef short short8 __attribute__((ext_vector_type(8)));
typedef float f32x4  __attribute__((ext_vector_type(4)));

// ---------- bf16 helpers ----------
__device__ __forceinline__ float bflo(uint32_t u) { union { uint32_t i; float f; } v; v.i = u << 16; return v.f; }
__device__ __forceinline__ float bfhi(uint32_t u) { union { uint32_t i; float f; } v; v.i = u & 0xFFFF0000u; return v.f; }
__device__ __forceinline__ float bf2f(uint16_t u) { union { uint32_t i; float f; } v; v.i = ((uint32_t)u) << 16; return v.f; }
// cheap bf16 pack: round-half-up (+0x8000) then v_perm_b32 pair-pack (1 op).
// Differs from RNE only on exact ties — negligible for absmax.
__device__ __forceinline__ uint32_t pkbf(float a, float b) {
  uint32_t ua = __float_as_uint(a) + 0x8000u;
  uint32_t ub = __float_as_uint(b) + 0x8000u;
  return __builtin_amdgcn_perm(ub, ua, 0x07060302u);  // [ua.b2,ua.b3,ub.b2,ub.b3]
}
__device__ __forceinline__ uint16_t bfr1(float f) {
  return (uint16_t)((__float_as_uint(f) + 0x8000u) >> 16);
}

// ---------- async global->LDS, 16B per lane (dest = wave base + lane*16) ----------
__device__ __forceinline__ void gload16(const void* g, void* l) {
  __builtin_amdgcn_global_load_lds(
      (const __attribute__((address_space(1))) uint32_t*)g,
      (__attribute__((address_space(3))) uint32_t*)l, 16, 0, 0);
}

// ---------- pack W^T bf16 [NWT][1024] for MFMA proj (LDS tile transpose) ----------
__global__ __launch_bounds__(256) void pack_wt_kernel(
    const float* __restrict__ Wq, const float* __restrict__ Wk,
    const float* __restrict__ Wv, uint16_t* __restrict__ Wt)
{
  __shared__ __align__(16) uint16_t Ts[64 * 68];
  int k0 = blockIdx.x * 64, n0 = blockIdx.y * 64;
  int t = threadIdx.x;
#pragma unroll
  for (int rep = 0; rep < 16; ++rep) {
    int li = rep * 256 + t;
    int kl = li >> 6, nl = li & 63;
    int k = k0 + kl, n = n0 + nl;
    float v = 0.f;
    if (n < 512)       v = Wq[k * 512 + n];
    else if (n < 1024) v = Wk[k * 512 + (n - 512)];
    else if (n < 1344) { int nn = n - 1024; v = Wv[((size_t)(nn >> 6) * 1024 + k) * 64 + (nn & 63)]; }
    Ts[kl * 68 + nl] = bfr1(v);
  }
  __syncthreads();
#pragma unroll
  for (int rep = 0; rep < 16; ++rep) {
    int li = rep * 256 + t;
    int nl = li >> 6, kl = li & 63;
    Wt[(size_t)(n0 + nl) * 1024 + k0 + kl] = Ts[kl * 68 + nl];
  }
}

// ---------- pack Wo[320][1024] fp32 -> WoT bf16 [1024][320] ----------
__global__ __launch_bounds__(256) void pack_wot_kernel(
    const float* __restrict__ Wo, uint16_t* __restrict__ WoT)
{
  __shared__ __align__(16) uint16_t Ts[64 * 68];
  int k0 = blockIdx.x * 64, n0 = blockIdx.y * 64;
  int t = threadIdx.x;
#pragma unroll
  for (int rep = 0; rep < 16; ++rep) {
    int li = rep * 256 + t;
    int kl = li >> 6, nl = li & 63;
    Ts[kl * 68 + nl] = bfr1(Wo[(size_t)(k0 + kl) * 1024 + n0 + nl]);
  }
  __syncthreads();
#pragma unroll
  for (int rep = 0; rep < 16; ++rep) {
    int li = rep * 256 + t;
    int nl = li >> 6, kl = li & 63;
    WoT[(size_t)(n0 + nl) * 320 + k0 + kl] = Ts[kl * 68 + nl];
  }
}

// ---------- x -> bf16 ----------
__global__ __launch_bounds__(256) void xbf_kernel(const float* __restrict__ x, uint16_t* __restrict__ xb)
{
  int i = (blockIdx.x * 256 + threadIdx.x) * 4;
  float4 v = *(const float4*)(x + i);
  uint2 o;
  o.x = pkbf(v.x, v.y);
  o.y = pkbf(v.z, v.w);
  *(uint2*)(xb + i) = o;
}

// ---------- top-2 of 5 (lax.top_k tie rule: lower index wins) ----------
__device__ __forceinline__ void top2_5(float g0, float g1, float g2, float g3, float g4,
                                       int& i1, float& b1, int& i2, float& b2) {
  i1 = 0; b1 = g0;
  if (g1 > b1) { b1 = g1; i1 = 1; }
  if (g2 > b1) { b1 = g2; i1 = 2; }
  if (g3 > b1) { b1 = g3; i1 = 3; }
  if (g4 > b1) { b1 = g4; i1 = 4; }
  i2 = -1; b2 = -__builtin_inff();
  if (i1 != 0 && g0 > b2) { b2 = g0; i2 = 0; }
  if (i1 != 1 && g1 > b2) { b2 = g1; i2 = 1; }
  if (i1 != 2 && g2 > b2) { b2 = g2; i2 = 2; }
  if (i1 != 3 && g3 > b2) { b2 = g3; i2 = 3; }
  if (i1 != 4 && g4 > b2) { b2 = g4; i2 = 4; }
}

// ---------- fused gate GEMM v4 (exact fp32, single kernel, no split-K) ----------
// 128 blocks x 256 threads. Wave = 64 lanes = 64 rows; wave w owns a
// wave-uniform 20-col group (w=0: Ws heads 0-3, w=1: Ws heads 4-7,
// w=2: Wd heads 0-3, w=3: Wd heads 4-7) -> W row loads are scalar
// (SGPR broadcast), off the LDS pipe. x staged per 128-k tile at stride
// 129 (odd -> 2 lanes/bank, conflict-free b32 reads, m136).
// Per-output fmaf chain: flat k ascending 0..1023 — BIT-IDENTICAL to the
// verified round-0 gate chain. Writes ONLY gsel (no new ws regions).
__global__ __launch_bounds__(256) void gate_v4_kernel(
    const float* __restrict__ x, const float* __restrict__ Ws,
    const float* __restrict__ Wd, uint4* __restrict__ gsel)
{
  __shared__ __align__(16) float xs[64 * 129];
  __shared__ uint32_t gx[64 * 8];
  int t = threadIdx.x;
  int m0 = blockIdx.x * 64;
  int w = __builtin_amdgcn_readfirstlane(t >> 6);   // wave id (uniform)
  int lane = t & 63;                                 // = row within block
  const float* __restrict__ Wg = (w < 2) ? Ws : Wd;  // uniform select
  int cbase = (w & 1) * 20;
  float acc[20];
#pragma unroll
  for (int j = 0; j < 20; ++j) acc[j] = 0.f;

  for (int kt = 0; kt < 8; ++kt) {
    __syncthreads();
    // stage x tile 64 rows x 128 k: global float4 coalesced, scalar LDS writes
#pragma unroll
    for (int rep = 0; rep < 8; ++rep) {
      int li = rep * 256 + t;
      int row = li >> 5, kg = li & 31;
      float4 v = *(const float4*)&x[(size_t)(m0 + row) * 1024 + kt * 128 + kg * 4];
      float* d = &xs[row * 129 + kg * 4];
      d[0] = v.x; d[1] = v.y; d[2] = v.z; d[3] = v.w;
    }
    __syncthreads();
#pragma unroll 8
    for (int k = 0; k < 128; ++k) {
      float xv = xs[lane * 129 + k];
      const float* wrow = &Wg[(size_t)(kt * 128 + k) * 40 + cbase];
#pragma unroll
      for (int j = 0; j < 20; ++j)
        acc[j] = fmaf(xv, wrow[j], acc[j]);
    }
  }

  // Each thread holds 4 complete heads (5 logits each), all indices static.
  int hbase = (w & 1) * 4;
  if (w >= 2) {   // Wd logits: out-expert selection only
#pragma unroll
    for (int hh = 0; hh < 4; ++hh) {
      int j1, j2; float c1, c2;
      top2_5(acc[hh * 5 + 0], acc[hh * 5 + 1], acc[hh * 5 + 2],
             acc[hh * 5 + 3], acc[hh * 5 + 4], j1, c1, j2, c2);
      gx[lane * 8 + hbase + hh] = (uint32_t)(j1 | (j2 << 3));
    }
  }
  __syncthreads();
  if (w < 2) {    // Ws logits: V-expert selection + sigmoid weights; assemble gsel
#pragma unroll
    for (int hh = 0; hh < 4; ++hh) {
      int i1, i2; float b1, b2;
      top2_5(acc[hh * 5 + 0], acc[hh * 5 + 1], acc[hh * 5 + 2],
             acc[hh * 5 + 3], acc[hh * 5 + 4], i1, b1, i2, b2);
      float w1 = 1.f / (1.f + __expf(-b1));
      float w2 = 1.f / (1.f + __expf(-b2));
      uint4 o;
      o.x = __float_as_uint(w1);
      o.y = __float_as_uint(w2);
      o.z = (uint32_t)(i1 | (i2 << 3));
      o.w = gx[lane * 8 + hbase + hh];
      gsel[(size_t)(m0 + lane) * 8 + hbase + hh] = o;
    }
  }
}

// ---------- proj MFMA GEMM (m97-style): global_load_lds into unpadded tiles ----------
__global__ __launch_bounds__(256) void proj_mfma_kernel(
    const uint16_t* __restrict__ xb, const uint16_t* __restrict__ Wt,
    uint16_t* __restrict__ proj)
{
  __shared__ __align__(16) uint16_t As[128 * 32];  // [m][k] unpadded (required by lds-DMA)
  __shared__ __align__(16) uint16_t Bs[128 * 32];  // [n][k]
  int t = threadIdx.x;
  int n0 = blockIdx.x * 128, m0 = blockIdx.y * 128;
  int w = t >> 6, lane = t & 63, q = lane >> 4, c = lane & 15;
  int wm = w & 1, wn = w >> 1;
  int lr = lane >> 2, lc = (lane & 3) * 8;   // 16 rows/chunk, 16B per lane
  f32x4 zf = {0.f, 0.f, 0.f, 0.f};
  f32x4 acc[4][4];
#pragma unroll
  for (int i = 0; i < 4; ++i)
#pragma unroll
    for (int j = 0; j < 4; ++j) acc[i][j] = zf;

  for (int kb = 0; kb < 32; ++kb) {
    __syncthreads();
#pragma unroll
    for (int j = 0; j < 2; ++j) {
      int row = w * 32 + j * 16 + lr;
      gload16(xb + (size_t)(m0 + row) * 1024 + kb * 32 + lc,
              &As[(w * 32 + j * 16) * 32 + lane * 8]);
      gload16(Wt + (size_t)(n0 + row) * 1024 + kb * 32 + lc,
              &Bs[(w * 32 + j * 16) * 32 + lane * 8]);
    }
    __syncthreads();
    short8 af[4], bfr[4];
#pragma unroll
    for (int i = 0; i < 4; ++i)
      af[i] = *(const short8*)&As[(wm * 64 + i * 16 + c) * 32 + q * 8];
#pragma unroll
    for (int j = 0; j < 4; ++j)
      bfr[j] = *(const short8*)&Bs[(wn * 64 + j * 16 + c) * 32 + q * 8];
#pragma unroll
    for (int i = 0; i < 4; ++i)
#pragma unroll
      for (int j = 0; j < 4; ++j)
        acc[i][j] = __builtin_amdgcn_mfma_f32_16x16x32_bf16(af[i], bfr[j], acc[i][j], 0, 0, 0);
  }
#pragma unroll
  for (int i = 0; i < 4; ++i)
#pragma unroll
    for (int j = 0; j < 4; ++j) {
      int col = n0 + wn * 64 + j * 16 + c;
      if (col < PLD) {
#pragma unroll
        for (int reg = 0; reg < 4; ++reg) {
          int row = m0 + wm * 64 + i * 16 + q * 4 + reg;
          proj[(size_t)row * PLD + col] = bfr1(acc[i][j][reg]);
        }
      }
    }
}

// ---------- out MFMA GEMM: zbuf[8192][320] @ WoT^T -> out fp32 [8192][1024] ----------
__global__ __launch_bounds__(256) void out_mfma_kernel(
    const uint16_t* __restrict__ zb, const uint16_t* __restrict__ WoT,
    float* __restrict__ out)
{
  __shared__ __align__(16) uint16_t As[128 * 32];
  __shared__ __align__(16) uint16_t Bs[128 * 32];
  int t = threadIdx.x;
  int n0 = blockIdx.x * 128, m0 = blockIdx.y * 128;
  int w = t >> 6, lane = t & 63, q = lane >> 4, c = lane & 15;
  int wm = w & 1, wn = w >> 1;
  int lr = lane >> 2, lc = (lane & 3) * 8;
  f32x4 zf = {0.f, 0.f, 0.f, 0.f};
  f32x4 acc[4][4];
#pragma unroll
  for (int i = 0; i < 4; ++i)
#pragma unroll
    for (int j = 0; j < 4; ++j) acc[i][j] = zf;

  for (int kb = 0; kb < 10; ++kb) {
    __syncthreads();
#pragma unroll
    for (int j = 0; j < 2; ++j) {
      int row = w * 32 + j * 16 + lr;
      gload16(zb + (size_t)(m0 + row) * 320 + kb * 32 + lc,
              &As[(w * 32 + j * 16) * 32 + lane * 8]);
      gload16(WoT + (size_t)(n0 + row) * 320 + kb * 32 + lc,
              &Bs[(w * 32 + j * 16) * 32 + lane * 8]);
    }
    __syncthreads();
    short8 af[4], bfr[4];
#pragma unroll
    for (int i = 0; i < 4; ++i)
      af[i] = *(const short8*)&As[(wm * 64 + i * 16 + c) * 32 + q * 8];
#pragma unroll
    for (int j = 0; j < 4; ++j)
      bfr[j] = *(const short8*)&Bs[(wn * 64 + j * 16 + c) * 32 + q * 8];
#pragma unroll
    for (int i = 0; i < 4; ++i)
#pragma unroll
      for (int j = 0; j < 4; ++j)
        acc[i][j] = __builtin_amdgcn_mfma_f32_16x16x32_bf16(af[i], bfr[j], acc[i][j], 0, 0, 0);
  }
#pragma unroll
  for (int i = 0; i < 4; ++i)
#pragma unroll
    for (int j = 0; j < 4; ++j) {
      int col = n0 + wn * 64 + j * 16 + c;
#pragma unroll
      for (int reg = 0; reg < 4; ++reg) {
        int row = m0 + wm * 64 + i * 16 + q * 4 + reg;
        out[(size_t)row * 1024 + col] = acc[i][j][reg];
      }
    }
}

// ---------- vbuild: v combine into d-major vt, cols PRE-PERMUTED (j' = (tt&15)*4+(tt>>4)) ----------
__global__ __launch_bounds__(256) void vbuild_kernel(
    const uint16_t* __restrict__ proj, const uint4* __restrict__ gsel,
    uint16_t* __restrict__ vt)
{
  int bi = blockIdx.x;            // 1024 = bh(32) x tb(32)
  int bh = bi >> 5, tb = bi & 31;
  int b = bh >> 3, h = bh & 7;
  int t = threadIdx.x;
  int tt = t & 63, dg = t >> 6;
  int m = b * 2048 + tb * 64 + tt;
  uint4 gs = gsel[m * 8 + h];
  float w1 = __uint_as_float(gs.x), w2 = __uint_as_float(gs.y);
  int i1 = gs.z & 7, i2 = (gs.z >> 3) & 7;
  const uint16_t* base = proj + (size_t)m * PLD + 1024;
  const uint4* p1 = (const uint4*)(base + i1 * 64 + dg * 16);
  const uint4* p2 = (const uint4*)(base + i2 * 64 + dg * 16);
  uint4 A0 = p1[0], A1 = p1[1], B0 = p2[0], B1 = p2[1];
  float v[16];
  v[0]  = w1*bflo(A0.x) + w2*bflo(B0.x); v[1]  = w1*bfhi(A0.x) + w2*bfhi(B0.x);
  v[2]  = w1*bflo(A0.y) + w2*bflo(B0.y); v[3]  = w1*bfhi(A0.y) + w2*bfhi(B0.y);
  v[4]  = w1*bflo(A0.z) + w2*bflo(B0.z); v[5]  = w1*bfhi(A0.z) + w2*bfhi(B0.z);
  v[6]  = w1*bflo(A0.w) + w2*bflo(B0.w); v[7]  = w1*bfhi(A0.w) + w2*bfhi(B0.w);
  v[8]  = w1*bflo(A1.x) + w2*bflo(B1.x); v[9]  = w1*bfhi(A1.x) + w2*bfhi(B1.x);
  v[10] = w1*bflo(A1.y) + w2*bflo(B1.y); v[11] = w1*bfhi(A1.y) + w2*bfhi(B1.y);
  v[12] = w1*bflo(A1.z) + w2*bflo(B1.z); v[13] = w1*bfhi(A1.z) + w2*bfhi(B1.z);
  v[14] = w1*bflo(A1.w) + w2*bflo(B1.w); v[15] = w1*bfhi(A1.w) + w2*bfhi(B1.w);
  int pcol = ((tt & 15) << 2) | (tt >> 4);
#pragma unroll
  for (int dd = 0; dd < 16; ++dd)
    vt[(size_t)(bh * 64 + dg * 16 + dd) * 2048 + tb * 64 + pcol] = bfr1(v[dd]);
}

// ---------- flash attention: 128-row Q tiles, MFMA 16x16x32 bf16, no-max softmax ----------
__global__ __launch_bounds__(256) void flash_mfma_kernel(
    const uint16_t* __restrict__ proj, const uint16_t* __restrict__ vt,
    uint16_t* __restrict__ attnb)
{
  __shared__ __align__(16) uint16_t Qs[128 * 72];  // [r][d], pre-scaled by dh^-0.5
  __shared__ __align__(16) uint16_t Ks[64 * 72];   // [j][d]
  __shared__ __align__(16) uint16_t Vs[64 * 72];   // [d][j']
  __shared__ __align__(16) uint16_t Ps[128 * 72];  // [r][j']
  int t = threadIdx.x;
  int bx = blockIdx.x;
  int qb = bx & 15, bh = bx >> 4;
  int h = bh & 7, b = bh >> 3;
  int w = t >> 6, lane = t & 63, q = lane >> 4, c = lane & 15;
  int srow = t >> 2, scq = t & 3;

  { // stage Q (128 rows), fold 0.125 scale (exact exponent shift -> pack lossless)
    int qrow = t >> 1, qhalf = t & 1;
    const uint4* p = (const uint4*)(proj + (size_t)(b * 2048 + qb * 128 + qrow) * PLD + h * 64 + qhalf * 32);
#pragma unroll
    for (int j = 0; j < 4; ++j) {
      uint4 vv = p[j];
      const uint16_t* s = (const uint16_t*)&vv;
      uint4 ov;
      ov.x = pkbf(bf2f(s[0]) * 0.125f, bf2f(s[1]) * 0.125f);
      ov.y = pkbf(bf2f(s[2]) * 0.125f, bf2f(s[3]) * 0.125f);
      ov.z = pkbf(bf2f(s[4]) * 0.125f, bf2f(s[5]) * 0.125f);
      ov.w = pkbf(bf2f(s[6]) * 0.125f, bf2f(s[7]) * 0.125f);
      *(uint4*)&Qs[qrow * 72 + qhalf * 32 + j * 8] = ov;
    }
  }
  __syncthreads();
  short8 aq[2][2];   // wave w owns q-rows [w*32, w*32+32): 2 row-tiles x 2 k-halves
#pragma unroll
  for (int rt = 0; rt < 2; ++rt)
#pragma unroll
    for (int hf = 0; hf < 2; ++hf)
      aq[rt][hf] = *(const short8*)&Qs[(w * 32 + rt * 16 + c) * 72 + hf * 32 + q * 8];

  f32x4 zf = {0.f, 0.f, 0.f, 0.f};
  f32x4 of[2][4];
  float ls[2][4];
#pragma unroll
  for (int rt = 0; rt < 2; ++rt)
#pragma unroll
    for (int nt = 0; nt < 4; ++nt) { of[rt][nt] = zf; ls[rt][nt] = 0.f; }

  for (int it = 0; it < 32; ++it) {
    __syncthreads();
    { // stage K tile [j][d] and V tile [d][j']
      const uint4* p = (const uint4*)(proj + (size_t)(b * 2048 + it * 64 + srow) * PLD + 512 + h * 64 + scq * 16);
      *(uint4*)&Ks[srow * 72 + scq * 16] = p[0];
      *(uint4*)&Ks[srow * 72 + scq * 16 + 8] = p[1];
      const uint4* pv = (const uint4*)(vt + (size_t)(bh * 64 + srow) * 2048 + it * 64 + scq * 16);
      *(uint4*)&Vs[srow * 72 + scq * 16] = pv[0];
      *(uint4*)&Vs[srow * 72 + scq * 16 + 8] = pv[1];
    }
    __syncthreads();

    // S = (Q*scale) K^T
    short8 bk[4][2];
#pragma unroll
    for (int nt = 0; nt < 4; ++nt) {
      bk[nt][0] = *(const short8*)&Ks[(nt * 16 + c) * 72 + q * 8];
      bk[nt][1] = *(const short8*)&Ks[(nt * 16 + c) * 72 + 32 + q * 8];
    }
    f32x4 sf[2][4];
#pragma unroll
    for (int rt = 0; rt < 2; ++rt)
#pragma unroll
      for (int nt = 0; nt < 4; ++nt) {
        f32x4 s = __builtin_amdgcn_mfma_f32_16x16x32_bf16(aq[rt][0], bk[nt][0], zf, 0, 0, 0);
        sf[rt][nt] = __builtin_amdgcn_mfma_f32_16x16x32_bf16(aq[rt][1], bk[nt][1], s, 0, 0, 0);
      }

    // p = exp(s); per-lane partial sums; packed b64 P write at j' = c*4+nt
#pragma unroll
    for (int rt = 0; rt < 2; ++rt)
#pragma unroll
      for (int reg = 0; reg < 4; ++reg) {
        float p0 = __expf(sf[rt][0][reg]);
        float p1 = __expf(sf[rt][1][reg]);
        float p2 = __expf(sf[rt][2][reg]);
        float p3 = __expf(sf[rt][3][reg]);
        ls[rt][reg] += (p0 + p1) + (p2 + p3);
        uint2 pw;
        pw.x = pkbf(p0, p1);
        pw.y = pkbf(p2, p3);
        *(uint2*)&Ps[(w * 32 + rt * 16 + q * 4 + reg) * 72 + c * 4] = pw;
      }

    // O += P V  (wave-private Ps rows; same-wave DS ops retire in order)
    short8 bv[4][2];
#pragma unroll
    for (int nt = 0; nt < 4; ++nt) {
      bv[nt][0] = *(const short8*)&Vs[(nt * 16 + c) * 72 + q * 8];
      bv[nt][1] = *(const short8*)&Vs[(nt * 16 + c) * 72 + 32 + q * 8];
    }
#pragma unroll
    for (int rt = 0; rt < 2; ++rt) {
      short8 ap0 = *(const short8*)&Ps[(w * 32 + rt * 16 + c) * 72 + q * 8];
      short8 ap1 = *(const short8*)&Ps[(w * 32 + rt * 16 + c) * 72 + 32 + q * 8];
#pragma unroll
      for (int nt = 0; nt < 4; ++nt) {
        of[rt][nt] = __builtin_amdgcn_mfma_f32_16x16x32_bf16(ap0, bv[nt][0], of[rt][nt], 0, 0, 0);
        of[rt][nt] = __builtin_amdgcn_mfma_f32_16x16x32_bf16(ap1, bv[nt][1], of[rt][nt], 0, 0, 0);
      }
    }
  }

#pragma unroll
  for (int rt = 0; rt < 2; ++rt)
#pragma unroll
    for (int reg = 0; reg < 4; ++reg) {
      float s = ls[rt][reg];
      s += __shfl_xor(s, 1);
      s += __shfl_xor(s, 2);
      s += __shfl_xor(s, 4);
      s += __shfl_xor(s, 8);
      float inv = 1.0f / s;
      size_t row = (size_t)(b * 2048 + qb * 128 + w * 32 + rt * 16 + q * 4 + reg);
#pragma unroll
      for (int nt = 0; nt < 4; ++nt)
        attnb[row * 512 + h * 64 + nt * 16 + c] = bfr1(of[rt][nt][reg] * inv);
    }
}

// ---------- zbuild: z[m][e*64+c] = sum_h mask_o[h,e] * attn[m][h*64+c] ----------
__global__ __launch_bounds__(64) void zbuild_kernel(
    const uint16_t* __restrict__ attnb, const uint32_t* __restrict__ gselw,
    uint16_t* __restrict__ zbuf)
{
  int m = blockIdx.x; int c = threadIdx.x;
  float acc[5] = {0.f, 0.f, 0.f, 0.f, 0.f};
#pragma unroll
  for (int h = 0; h < 8; ++h) {
    uint32_t sel = gselw[(m * 8 + h) * 4 + 3];
    int e1 = sel & 7, e2 = (sel >> 3) & 7;
    float a = bf2f(attnb[(size_t)m * 512 + h * 64 + c]);
#pragma unroll
    for (int e = 0; e < 5; ++e)
      acc[e] += (e == e1 || e == e2) ? a : 0.f;
  }
#pragma unroll
  for (int e = 0; e < 5; ++e)
    zbuf[(size_t)m * 320 + e * 64 + c] = bfr1(acc[e]);
}

// ---------- launch ----------
extern "C" void kernel_launch(void* const* d_in, const int* in_sizes, int n_in,
                              void* d_out, int out_size, void* d_ws, size_t ws_size,
                              hipStream_t stream) {
  const float* x  = (const float*)d_in[0];
  const float* Wq = (const float*)d_in[1];
  const float* Wk = (const float*)d_in[2];
  const float* Ws = (const float*)d_in[3];
  const float* Wd = (const float*)d_in[4];
  const float* Wv = (const float*)d_in[5];
  const float* Wo = (const float*)d_in[6];
  float* out = (float*)d_out;

  // workspace carve, lifetime-aliased; high-water 51,773,440 B
  char* ws = (char*)d_ws;
  uint4*    gsel  = (uint4*)   (ws);                  // [0, 1,048,576)
  uint16_t* WoT   = (uint16_t*)(ws + 1048576);        // [.., 1,703,936)
  uint16_t* Wt    = (uint16_t*)(ws + 1703936);        // [.., 4,587,520)  dead after proj
  uint16_t* xb    = (uint16_t*)(ws + 4587520);        // [.., 21,364,736) dead after proj
  uint16_t* proj  = (uint16_t*)(ws + 21364736);       // [.., 43,384,832)
  uint16_t* vt    = (uint16_t*)(ws + 43384832);       // [.., 51,773,440)
  uint16_t* attnb = (uint16_t*)(ws + 1703936);        // alias Wt+xb (dead)
  uint16_t* zbuf  = (uint16_t*)(ws + 10092544);       // alias xb tail

  gate_v4_kernel<<<MM / 64, 256, 0, stream>>>(x, Ws, Wd, gsel);
  pack_wt_kernel<<<dim3(16, 22), 256, 0, stream>>>(Wq, Wk, Wv, Wt);
  pack_wot_kernel<<<dim3(5, 16), 256, 0, stream>>>(Wo, WoT);
  xbf_kernel<<<(MM * DD / 4) / 256, 256, 0, stream>>>(x, xb);
  proj_mfma_kernel<<<dim3(NWT / 128, MM / 128), 256, 0, stream>>>(xb, Wt, proj);
  vbuild_kernel<<<32 * 32, 256, 0, stream>>>(proj, gsel, vt);
  flash_mfma_kernel<<<BB * HH * (TT / 128), 256, 0, stream>>>(proj, vt, attnb);
  zbuild_kernel<<<MM, 64, 0, stream>>>(attnb, (const uint32_t*)gsel, zbuf);
  out_mfma_kernel<<<dim3(DD / 128, MM / 128), 256, 0, stream>>>(zbuf, WoT, out);
}

// Round 3
// 273.428 us; speedup vs baseline: 1.4564x; 1.4564x over previous
//
#include <hip/hip_runtime.h>
#include <cstdint>
#include <cstddef>

// Problem constants
#define BB 4
#define TT 2048
#define DD 1024
#define HH 8
#define DH 64
#define EE 5
#define MM (BB*TT)          // 8192 rows
#define PLD 1344            // proj leading dim (q 512 | k 512 | xv 320)
#define NWT 1408            // padded N for MFMA proj (11 * 128)

typedef short short8 __attribute__((ext_vector_type(8)));
typedef float f32x4  __attribute__((ext_vector_type(4)));

// ---------- bf16 helpers ----------
__device__ __forceinline__ float bflo(uint32_t u) { union { uint32_t i; float f; } v; v.i = u << 16; return v.f; }
__device__ __forceinline__ float bfhi(uint32_t u) { union { uint32_t i; float f; } v; v.i = u & 0xFFFF0000u; return v.f; }
__device__ __forceinline__ float bf2f(uint16_t u) { union { uint32_t i; float f; } v; v.i = ((uint32_t)u) << 16; return v.f; }
// cheap bf16 pack: round-half-up (+0x8000) then v_perm_b32 pair-pack (1 op).
// Differs from RNE only on exact ties — negligible for absmax.
__device__ __forceinline__ uint32_t pkbf(float a, float b) {
  uint32_t ua = __float_as_uint(a) + 0x8000u;
  uint32_t ub = __float_as_uint(b) + 0x8000u;
  return __builtin_amdgcn_perm(ub, ua, 0x07060302u);  // [ua.b2,ua.b3,ub.b2,ub.b3]
}
__device__ __forceinline__ uint16_t bfr1(float f) {
  return (uint16_t)((__float_as_uint(f) + 0x8000u) >> 16);
}

// ---------- async global->LDS, 16B per lane (dest = wave base + lane*16) ----------
__device__ __forceinline__ void gload16(const void* g, void* l) {
  __builtin_amdgcn_global_load_lds(
      (const __attribute__((address_space(1))) uint32_t*)g,
      (__attribute__((address_space(3))) uint32_t*)l, 16, 0, 0);
}

// ---------- pack W^T bf16 [NWT][1024] for MFMA proj (LDS tile transpose) ----------
__global__ __launch_bounds__(256) void pack_wt_kernel(
    const float* __restrict__ Wq, const float* __restrict__ Wk,
    const float* __restrict__ Wv, uint16_t* __restrict__ Wt)
{
  __shared__ __align__(16) uint16_t Ts[64 * 68];
  int k0 = blockIdx.x * 64, n0 = blockIdx.y * 64;
  int t = threadIdx.x;
#pragma unroll
  for (int rep = 0; rep < 16; ++rep) {
    int li = rep * 256 + t;
    int kl = li >> 6, nl = li & 63;
    int k = k0 + kl, n = n0 + nl;
    float v = 0.f;
    if (n < 512)       v = Wq[k * 512 + n];
    else if (n < 1024) v = Wk[k * 512 + (n - 512)];
    else if (n < 1344) { int nn = n - 1024; v = Wv[((size_t)(nn >> 6) * 1024 + k) * 64 + (nn & 63)]; }
    Ts[kl * 68 + nl] = bfr1(v);
  }
  __syncthreads();
#pragma unroll
  for (int rep = 0; rep < 16; ++rep) {
    int li = rep * 256 + t;
    int nl = li >> 6, kl = li & 63;
    Wt[(size_t)(n0 + nl) * 1024 + k0 + kl] = Ts[kl * 68 + nl];
  }
}

// ---------- pack Wo[320][1024] fp32 -> WoT bf16 [1024][320] ----------
__global__ __launch_bounds__(256) void pack_wot_kernel(
    const float* __restrict__ Wo, uint16_t* __restrict__ WoT)
{
  __shared__ __align__(16) uint16_t Ts[64 * 68];
  int k0 = blockIdx.x * 64, n0 = blockIdx.y * 64;
  int t = threadIdx.x;
#pragma unroll
  for (int rep = 0; rep < 16; ++rep) {
    int li = rep * 256 + t;
    int kl = li >> 6, nl = li & 63;
    Ts[kl * 68 + nl] = bfr1(Wo[(size_t)(k0 + kl) * 1024 + n0 + nl]);
  }
  __syncthreads();
#pragma unroll
  for (int rep = 0; rep < 16; ++rep) {
    int li = rep * 256 + t;
    int nl = li >> 6, kl = li & 63;
    WoT[(size_t)(n0 + nl) * 320 + k0 + kl] = Ts[kl * 68 + nl];
  }
}

// ---------- x -> bf16 ----------
__global__ __launch_bounds__(256) void xbf_kernel(const float* __restrict__ x, uint16_t* __restrict__ xb)
{
  int i = (blockIdx.x * 256 + threadIdx.x) * 4;
  float4 v = *(const float4*)(x + i);
  uint2 o;
  o.x = pkbf(v.x, v.y);
  o.y = pkbf(v.z, v.w);
  *(uint2*)(xb + i) = o;
}

// ---------- top-2 of 5 (lax.top_k tie rule: lower index wins) ----------
__device__ __forceinline__ void top2_5(float g0, float g1, float g2, float g3, float g4,
                                       int& i1, float& b1, int& i2, float& b2) {
  i1 = 0; b1 = g0;
  if (g1 > b1) { b1 = g1; i1 = 1; }
  if (g2 > b1) { b1 = g2; i1 = 2; }
  if (g3 > b1) { b1 = g3; i1 = 3; }
  if (g4 > b1) { b1 = g4; i1 = 4; }
  i2 = -1; b2 = -__builtin_inff();
  if (i1 != 0 && g0 > b2) { b2 = g0; i2 = 0; }
  if (i1 != 1 && g1 > b2) { b2 = g1; i2 = 1; }
  if (i1 != 2 && g2 > b2) { b2 = g2; i2 = 2; }
  if (i1 != 3 && g3 > b2) { b2 = g3; i2 = 3; }
  if (i1 != 4 && g4 > b2) { b2 = g4; i2 = 4; }
}

// ---------- gate helpers: 20-wide uniform W batch + fma ----------
__device__ __forceinline__ void ldw20(float* d, const float* __restrict__ p) {
#pragma unroll
  for (int j = 0; j < 20; ++j) d[j] = p[j];
}
__device__ __forceinline__ void fma20(float* acc, const float* wv, float xv) {
#pragma unroll
  for (int j = 0; j < 20; ++j) acc[j] = fmaf(xv, wv[j], acc[j]);
}

// ---------- fused gate GEMM v5 (exact fp32, in-block 4-way K-split) ----------
// Grid 128 x 1024 threads (16 waves = 4 waves/SIMD -> SMEM latency hidden by
// wave interleave; round-2's v4 died at 1 wave/SIMD). lane = row (64 rows).
// Wave (cg, kq): cg in 0..3 = wave-uniform 20-col group (Ws h0-3 | Ws h4-7 |
// Wd h0-3 | Wd h4-7) -> W row loads are scalar s_load (0 VALU/LDS cost),
// ping-pong double-buffered (wc/wn) so each batch is issued one 20-FMA block
// before use. kq in 0..3 = in-TILE k-split: wave computes k in [kq*32,kq*32+32)
// of EVERY 128-k tile (no barrier serialization). x tile in LDS stride-132:
// lane*33 mod 32 -> 2-way bank alias (free, m136), 16B-aligned float4 reads.
// K-partials combined in-LDS, fixed tree (s0+s1)+(s2+s3) — deterministic,
// no global partial buffers. Writes ONLY gsel; words 0-2 by Ws waves,
// word 3 by Wd waves (disjoint dwords).
__global__ __launch_bounds__(1024) void gate_v5_kernel(
    const float* __restrict__ x, const float* __restrict__ Ws,
    const float* __restrict__ Wd, uint32_t* __restrict__ gsel32)
{
  __shared__ __align__(16) float xs[64 * 132];   // 33,792 B
  int t = threadIdx.x;
  int m0 = blockIdx.x * 64;
  int w = t >> 6, lane = t & 63;
  int cg = __builtin_amdgcn_readfirstlane(w & 3);
  int kq = __builtin_amdgcn_readfirstlane(w >> 2);
  const float* __restrict__ Wg = (cg < 2) ? Ws : Wd;
  const float* __restrict__ wbase = Wg + (size_t)(kq * 32) * 40 + (cg & 1) * 20;

  float acc[20];
#pragma unroll
  for (int j = 0; j < 20; ++j) acc[j] = 0.f;

  for (int tile = 0; tile < 8; ++tile) {
    __syncthreads();
    // stage x tile 64 rows x 128 k: float4 coalesced global, float4 LDS stores
#pragma unroll
    for (int rep = 0; rep < 2; ++rep) {
      int li = rep * 1024 + t;
      int row = li >> 5, kg = li & 31;
      float4 v = *(const float4*)&x[(size_t)(m0 + row) * 1024 + tile * 128 + kg * 4];
      *(float4*)&xs[row * 132 + kg * 4] = v;
    }
    __syncthreads();

    const float* wp = wbase + (size_t)tile * 128 * 40;
    const float* xp = &xs[lane * 132 + kq * 32];
    float wc[20], wn[20];
    ldw20(wc, wp);                       // k-local 0
#pragma unroll
    for (int k4 = 0; k4 < 8; ++k4) {
      float4 xv = *(const float4*)&xp[k4 * 4];
      ldw20(wn, wp + (size_t)(k4 * 4 + 1) * 40);
      fma20(acc, wc, xv.x);              // k = 4*k4+0
      ldw20(wc, wp + (size_t)(k4 * 4 + 2) * 40);
      fma20(acc, wn, xv.y);              // k = 4*k4+1
      ldw20(wn, wp + (size_t)(k4 * 4 + 3) * 40);
      fma20(acc, wc, xv.z);              // k = 4*k4+2
      if (k4 < 7) ldw20(wc, wp + (size_t)(k4 * 4 + 4) * 40);
      fma20(acc, wn, xv.w);              // k = 4*k4+3
    }
  }

  // ---- in-LDS K-split reduction, tree (s0+s1)+(s2+s3), slices ascending ----
  float* red = xs;                       // [cg][lane][21] = 5376 floats, fits
  int ro = cg * (64 * 21) + lane * 21;
  __syncthreads();                       // xs (x tile) dead
  if (kq == 1) {
#pragma unroll
    for (int j = 0; j < 20; ++j) red[ro + j] = acc[j];
  }
  __syncthreads();
  if (kq == 0) {
#pragma unroll
    for (int j = 0; j < 20; ++j) acc[j] += red[ro + j];   // s0+s1
  }
  __syncthreads();
  if (kq == 3) {
#pragma unroll
    for (int j = 0; j < 20; ++j) red[ro + j] = acc[j];
  }
  __syncthreads();
  if (kq == 2) {
#pragma unroll
    for (int j = 0; j < 20; ++j) acc[j] += red[ro + j];   // s2+s3
  }
  __syncthreads();
  if (kq == 2) {
#pragma unroll
    for (int j = 0; j < 20; ++j) red[ro + j] = acc[j];
  }
  __syncthreads();

  if (kq == 0) {
#pragma unroll
    for (int j = 0; j < 20; ++j) acc[j] += red[ro + j];   // (s0+s1)+(s2+s3)
    int m = m0 + lane;
    if (cg < 2) {      // Ws: V-expert selection + sigmoid weights (words 0-2)
#pragma unroll
      for (int hh = 0; hh < 4; ++hh) {
        int i1, i2; float b1, b2;
        top2_5(acc[hh * 5 + 0], acc[hh * 5 + 1], acc[hh * 5 + 2],
               acc[hh * 5 + 3], acc[hh * 5 + 4], i1, b1, i2, b2);
        float w1 = 1.f / (1.f + __expf(-b1));
        float w2 = 1.f / (1.f + __expf(-b2));
        uint32_t* g = gsel32 + ((size_t)m * 8 + (cg & 1) * 4 + hh) * 4;
        g[0] = __float_as_uint(w1);
        g[1] = __float_as_uint(w2);
        g[2] = (uint32_t)(i1 | (i2 << 3));
      }
    } else {           // Wd: out-expert selection only (word 3)
#pragma unroll
      for (int hh = 0; hh < 4; ++hh) {
        int j1, j2; float c1, c2;
        top2_5(acc[hh * 5 + 0], acc[hh * 5 + 1], acc[hh * 5 + 2],
               acc[hh * 5 + 3], acc[hh * 5 + 4], j1, c1, j2, c2);
        uint32_t* g = gsel32 + ((size_t)m * 8 + (cg & 1) * 4 + hh) * 4;
        g[3] = (uint32_t)(j1 | (j2 << 3));
      }
    }
  }
}

// ---------- proj MFMA GEMM (m97-style): global_load_lds into unpadded tiles ----------
__global__ __launch_bounds__(256) void proj_mfma_kernel(
    const uint16_t* __restrict__ xb, const uint16_t* __restrict__ Wt,
    uint16_t* __restrict__ proj)
{
  __shared__ __align__(16) uint16_t As[128 * 32];  // [m][k] unpadded (required by lds-DMA)
  __shared__ __align__(16) uint16_t Bs[128 * 32];  // [n][k]
  int t = threadIdx.x;
  int n0 = blockIdx.x * 128, m0 = blockIdx.y * 128;
  int w = t >> 6, lane = t & 63, q = lane >> 4, c = lane & 15;
  int wm = w & 1, wn = w >> 1;
  int lr = lane >> 2, lc = (lane & 3) * 8;   // 16 rows/chunk, 16B per lane
  f32x4 zf = {0.f, 0.f, 0.f, 0.f};
  f32x4 acc[4][4];
#pragma unroll
  for (int i = 0; i < 4; ++i)
#pragma unroll
    for (int j = 0; j < 4; ++j) acc[i][j] = zf;

  for (int kb = 0; kb < 32; ++kb) {
    __syncthreads();
#pragma unroll
    for (int j = 0; j < 2; ++j) {
      int row = w * 32 + j * 16 + lr;
      gload16(xb + (size_t)(m0 + row) * 1024 + kb * 32 + lc,
              &As[(w * 32 + j * 16) * 32 + lane * 8]);
      gload16(Wt + (size_t)(n0 + row) * 1024 + kb * 32 + lc,
              &Bs[(w * 32 + j * 16) * 32 + lane * 8]);
    }
    __syncthreads();
    short8 af[4], bfr[4];
#pragma unroll
    for (int i = 0; i < 4; ++i)
      af[i] = *(const short8*)&As[(wm * 64 + i * 16 + c) * 32 + q * 8];
#pragma unroll
    for (int j = 0; j < 4; ++j)
      bfr[j] = *(const short8*)&Bs[(wn * 64 + j * 16 + c) * 32 + q * 8];
#pragma unroll
    for (int i = 0; i < 4; ++i)
#pragma unroll
      for (int j = 0; j < 4; ++j)
        acc[i][j] = __builtin_amdgcn_mfma_f32_16x16x32_bf16(af[i], bfr[j], acc[i][j], 0, 0, 0);
  }
#pragma unroll
  for (int i = 0; i < 4; ++i)
#pragma unroll
    for (int j = 0; j < 4; ++j) {
      int col = n0 + wn * 64 + j * 16 + c;
      if (col < PLD) {
#pragma unroll
        for (int reg = 0; reg < 4; ++reg) {
          int row = m0 + wm * 64 + i * 16 + q * 4 + reg;
          proj[(size_t)row * PLD + col] = bfr1(acc[i][j][reg]);
        }
      }
    }
}

// ---------- out MFMA GEMM: zbuf[8192][320] @ WoT^T -> out fp32 [8192][1024] ----------
__global__ __launch_bounds__(256) void out_mfma_kernel(
    const uint16_t* __restrict__ zb, const uint16_t* __restrict__ WoT,
    float* __restrict__ out)
{
  __shared__ __align__(16) uint16_t As[128 * 32];
  __shared__ __align__(16) uint16_t Bs[128 * 32];
  int t = threadIdx.x;
  int n0 = blockIdx.x * 128, m0 = blockIdx.y * 128;
  int w = t >> 6, lane = t & 63, q = lane >> 4, c = lane & 15;
  int wm = w & 1, wn = w >> 1;
  int lr = lane >> 2, lc = (lane & 3) * 8;
  f32x4 zf = {0.f, 0.f, 0.f, 0.f};
  f32x4 acc[4][4];
#pragma unroll
  for (int i = 0; i < 4; ++i)
#pragma unroll
    for (int j = 0; j < 4; ++j) acc[i][j] = zf;

  for (int kb = 0; kb < 10; ++kb) {
    __syncthreads();
#pragma unroll
    for (int j = 0; j < 2; ++j) {
      int row = w * 32 + j * 16 + lr;
      gload16(zb + (size_t)(m0 + row) * 320 + kb * 32 + lc,
              &As[(w * 32 + j * 16) * 32 + lane * 8]);
      gload16(WoT + (size_t)(n0 + row) * 320 + kb * 32 + lc,
              &Bs[(w * 32 + j * 16) * 32 + lane * 8]);
    }
    __syncthreads();
    short8 af[4], bfr[4];
#pragma unroll
    for (int i = 0; i < 4; ++i)
      af[i] = *(const short8*)&As[(wm * 64 + i * 16 + c) * 32 + q * 8];
#pragma unroll
    for (int j = 0; j < 4; ++j)
      bfr[j] = *(const short8*)&Bs[(wn * 64 + j * 16 + c) * 32 + q * 8];
#pragma unroll
    for (int i = 0; i < 4; ++i)
#pragma unroll
      for (int j = 0; j < 4; ++j)
        acc[i][j] = __builtin_amdgcn_mfma_f32_16x16x32_bf16(af[i], bfr[j], acc[i][j], 0, 0, 0);
  }
#pragma unroll
  for (int i = 0; i < 4; ++i)
#pragma unroll
    for (int j = 0; j < 4; ++j) {
      int col = n0 + wn * 64 + j * 16 + c;
#pragma unroll
      for (int reg = 0; reg < 4; ++reg) {
        int row = m0 + wm * 64 + i * 16 + q * 4 + reg;
        out[(size_t)row * 1024 + col] = acc[i][j][reg];
      }
    }
}

// ---------- vbuild: v combine into d-major vt, cols PRE-PERMUTED (j' = (tt&15)*4+(tt>>4)) ----------
__global__ __launch_bounds__(256) void vbuild_kernel(
    const uint16_t* __restrict__ proj, const uint4* __restrict__ gsel,
    uint16_t* __restrict__ vt)
{
  int bi = blockIdx.x;            // 1024 = bh(32) x tb(32)
  int bh = bi >> 5, tb = bi & 31;
  int b = bh >> 3, h = bh & 7;
  int t = threadIdx.x;
  int tt = t & 63, dg = t >> 6;
  int m = b * 2048 + tb * 64 + tt;
  uint4 gs = gsel[m * 8 + h];
  float w1 = __uint_as_float(gs.x), w2 = __uint_as_float(gs.y);
  int i1 = gs.z & 7, i2 = (gs.z >> 3) & 7;
  const uint16_t* base = proj + (size_t)m * PLD + 1024;
  const uint4* p1 = (const uint4*)(base + i1 * 64 + dg * 16);
  const uint4* p2 = (const uint4*)(base + i2 * 64 + dg * 16);
  uint4 A0 = p1[0], A1 = p1[1], B0 = p2[0], B1 = p2[1];
  float v[16];
  v[0]  = w1*bflo(A0.x) + w2*bflo(B0.x); v[1]  = w1*bfhi(A0.x) + w2*bfhi(B0.x);
  v[2]  = w1*bflo(A0.y) + w2*bflo(B0.y); v[3]  = w1*bfhi(A0.y) + w2*bfhi(B0.y);
  v[4]  = w1*bflo(A0.z) + w2*bflo(B0.z); v[5]  = w1*bfhi(A0.z) + w2*bfhi(B0.z);
  v[6]  = w1*bflo(A0.w) + w2*bflo(B0.w); v[7]  = w1*bfhi(A0.w) + w2*bfhi(B0.w);
  v[8]  = w1*bflo(A1.x) + w2*bflo(B1.x); v[9]  = w1*bfhi(A1.x) + w2*bfhi(B1.x);
  v[10] = w1*bflo(A1.y) + w2*bflo(B1.y); v[11] = w1*bfhi(A1.y) + w2*bfhi(B1.y);
  v[12] = w1*bflo(A1.z) + w2*bflo(B1.z); v[13] = w1*bfhi(A1.z) + w2*bfhi(B1.z);
  v[14] = w1*bflo(A1.w) + w2*bflo(B1.w); v[15] = w1*bfhi(A1.w) + w2*bfhi(B1.w);
  int pcol = ((tt & 15) << 2) | (tt >> 4);
#pragma unroll
  for (int dd = 0; dd < 16; ++dd)
    vt[(size_t)(bh * 64 + dg * 16 + dd) * 2048 + tb * 64 + pcol] = bfr1(v[dd]);
}

// ---------- flash attention: 128-row Q tiles, MFMA 16x16x32 bf16, no-max softmax ----------
__global__ __launch_bounds__(256) void flash_mfma_kernel(
    const uint16_t* __restrict__ proj, const uint16_t* __restrict__ vt,
    uint16_t* __restrict__ attnb)
{
  __shared__ __align__(16) uint16_t Qs[128 * 72];  // [r][d], pre-scaled by dh^-0.5
  __shared__ __align__(16) uint16_t Ks[64 * 72];   // [j][d]
  __shared__ __align__(16) uint16_t Vs[64 * 72];   // [d][j']
  __shared__ __align__(16) uint16_t Ps[128 * 72];  // [r][j']
  int t = threadIdx.x;
  int bx = blockIdx.x;
  int qb = bx & 15, bh = bx >> 4;
  int h = bh & 7, b = bh >> 3;
  int w = t >> 6, lane = t & 63, q = lane >> 4, c = lane & 15;
  int srow = t >> 2, scq = t & 3;

  { // stage Q (128 rows), fold 0.125 scale (exact exponent shift -> pack lossless)
    int qrow = t >> 1, qhalf = t & 1;
    const uint4* p = (const uint4*)(proj + (size_t)(b * 2048 + qb * 128 + qrow) * PLD + h * 64 + qhalf * 32);
#pragma unroll
    for (int j = 0; j < 4; ++j) {
      uint4 vv = p[j];
      const uint16_t* s = (const uint16_t*)&vv;
      uint4 ov;
      ov.x = pkbf(bf2f(s[0]) * 0.125f, bf2f(s[1]) * 0.125f);
      ov.y = pkbf(bf2f(s[2]) * 0.125f, bf2f(s[3]) * 0.125f);
      ov.z = pkbf(bf2f(s[4]) * 0.125f, bf2f(s[5]) * 0.125f);
      ov.w = pkbf(bf2f(s[6]) * 0.125f, bf2f(s[7]) * 0.125f);
      *(uint4*)&Qs[qrow * 72 + qhalf * 32 + j * 8] = ov;
    }
  }
  __syncthreads();
  short8 aq[2][2];   // wave w owns q-rows [w*32, w*32+32): 2 row-tiles x 2 k-halves
#pragma unroll
  for (int rt = 0; rt < 2; ++rt)
#pragma unroll
    for (int hf = 0; hf < 2; ++hf)
      aq[rt][hf] = *(const short8*)&Qs[(w * 32 + rt * 16 + c) * 72 + hf * 32 + q * 8];

  f32x4 zf = {0.f, 0.f, 0.f, 0.f};
  f32x4 of[2][4];
  float ls[2][4];
#pragma unroll
  for (int rt = 0; rt < 2; ++rt)
#pragma unroll
    for (int nt = 0; nt < 4; ++nt) { of[rt][nt] = zf; ls[rt][nt] = 0.f; }

  for (int it = 0; it < 32; ++it) {
    __syncthreads();
    { // stage K tile [j][d] and V tile [d][j']
      const uint4* p = (const uint4*)(proj + (size_t)(b * 2048 + it * 64 + srow) * PLD + 512 + h * 64 + scq * 16);
      *(uint4*)&Ks[srow * 72 + scq * 16] = p[0];
      *(uint4*)&Ks[srow * 72 + scq * 16 + 8] = p[1];
      const uint4* pv = (const uint4*)(vt + (size_t)(bh * 64 + srow) * 2048 + it * 64 + scq * 16);
      *(uint4*)&Vs[srow * 72 + scq * 16] = pv[0];
      *(uint4*)&Vs[srow * 72 + scq * 16 + 8] = pv[1];
    }
    __syncthreads();

    // S = (Q*scale) K^T
    short8 bk[4][2];
#pragma unroll
    for (int nt = 0; nt < 4; ++nt) {
      bk[nt][0] = *(const short8*)&Ks[(nt * 16 + c) * 72 + q * 8];
      bk[nt][1] = *(const short8*)&Ks[(nt * 16 + c) * 72 + 32 + q * 8];
    }
    f32x4 sf[2][4];
#pragma unroll
    for (int rt = 0; rt < 2; ++rt)
#pragma unroll
      for (int nt = 0; nt < 4; ++nt) {
        f32x4 s = __builtin_amdgcn_mfma_f32_16x16x32_bf16(aq[rt][0], bk[nt][0], zf, 0, 0, 0);
        sf[rt][nt] = __builtin_amdgcn_mfma_f32_16x16x32_bf16(aq[rt][1], bk[nt][1], s, 0, 0, 0);
      }

    // p = exp(s); per-lane partial sums; packed b64 P write at j' = c*4+nt
#pragma unroll
    for (int rt = 0; rt < 2; ++rt)
#pragma unroll
      for (int reg = 0; reg < 4; ++reg) {
        float p0 = __expf(sf[rt][0][reg]);
        float p1 = __expf(sf[rt][1][reg]);
        float p2 = __expf(sf[rt][2][reg]);
        float p3 = __expf(sf[rt][3][reg]);
        ls[rt][reg] += (p0 + p1) + (p2 + p3);
        uint2 pw;
        pw.x = pkbf(p0, p1);
        pw.y = pkbf(p2, p3);
        *(uint2*)&Ps[(w * 32 + rt * 16 + q * 4 + reg) * 72 + c * 4] = pw;
      }

    // O += P V  (wave-private Ps rows; same-wave DS ops retire in order)
    short8 bv[4][2];
#pragma unroll
    for (int nt = 0; nt < 4; ++nt) {
      bv[nt][0] = *(const short8*)&Vs[(nt * 16 + c) * 72 + q * 8];
      bv[nt][1] = *(const short8*)&Vs[(nt * 16 + c) * 72 + 32 + q * 8];
    }
#pragma unroll
    for (int rt = 0; rt < 2; ++rt) {
      short8 ap0 = *(const short8*)&Ps[(w * 32 + rt * 16 + c) * 72 + q * 8];
      short8 ap1 = *(const short8*)&Ps[(w * 32 + rt * 16 + c) * 72 + 32 + q * 8];
#pragma unroll
      for (int nt = 0; nt < 4; ++nt) {
        of[rt][nt] = __builtin_amdgcn_mfma_f32_16x16x32_bf16(ap0, bv[nt][0], of[rt][nt], 0, 0, 0);
        of[rt][nt] = __builtin_amdgcn_mfma_f32_16x16x32_bf16(ap1, bv[nt][1], of[rt][nt], 0, 0, 0);
      }
    }
  }

#pragma unroll
  for (int rt = 0; rt < 2; ++rt)
#pragma unroll
    for (int reg = 0; reg < 4; ++reg) {
      float s = ls[rt][reg];
      s += __shfl_xor(s, 1);
      s += __shfl_xor(s, 2);
      s += __shfl_xor(s, 4);
      s += __shfl_xor(s, 8);
      float inv = 1.0f / s;
      size_t row = (size_t)(b * 2048 + qb * 128 + w * 32 + rt * 16 + q * 4 + reg);
#pragma unroll
      for (int nt = 0; nt < 4; ++nt)
        attnb[row * 512 + h * 64 + nt * 16 + c] = bfr1(of[rt][nt][reg] * inv);
    }
}

// ---------- zbuild: z[m][e*64+c] = sum_h mask_o[h,e] * attn[m][h*64+c] ----------
__global__ __launch_bounds__(64) void zbuild_kernel(
    const uint16_t* __restrict__ attnb, const uint32_t* __restrict__ gselw,
    uint16_t* __restrict__ zbuf)
{
  int m = blockIdx.x; int c = threadIdx.x;
  float acc[5] = {0.f, 0.f, 0.f, 0.f, 0.f};
#pragma unroll
  for (int h = 0; h < 8; ++h) {
    uint32_t sel = gselw[(m * 8 + h) * 4 + 3];
    int e1 = sel & 7, e2 = (sel >> 3) & 7;
    float a = bf2f(attnb[(size_t)m * 512 + h * 64 + c]);
#pragma unroll
    for (int e = 0; e < 5; ++e)
      acc[e] += (e == e1 || e == e2) ? a : 0.f;
  }
#pragma unroll
  for (int e = 0; e < 5; ++e)
    zbuf[(size_t)m * 320 + e * 64 + c] = bfr1(acc[e]);
}

// ---------- launch ----------
extern "C" void kernel_launch(void* const* d_in, const int* in_sizes, int n_in,
                              void* d_out, int out_size, void* d_ws, size_t ws_size,
                              hipStream_t stream) {
  const float* x  = (const float*)d_in[0];
  const float* Wq = (const float*)d_in[1];
  const float* Wk = (const float*)d_in[2];
  const float* Ws = (const float*)d_in[3];
  const float* Wd = (const float*)d_in[4];
  const float* Wv = (const float*)d_in[5];
  const float* Wo = (const float*)d_in[6];
  float* out = (float*)d_out;

  // workspace carve, lifetime-aliased; high-water 51,773,440 B
  char* ws = (char*)d_ws;
  uint4*    gsel  = (uint4*)   (ws);                  // [0, 1,048,576)
  uint16_t* WoT   = (uint16_t*)(ws + 1048576);        // [.., 1,703,936)
  uint16_t* Wt    = (uint16_t*)(ws + 1703936);        // [.., 4,587,520)  dead after proj
  uint16_t* xb    = (uint16_t*)(ws + 4587520);        // [.., 21,364,736) dead after proj
  uint16_t* proj  = (uint16_t*)(ws + 21364736);       // [.., 43,384,832)
  uint16_t* vt    = (uint16_t*)(ws + 43384832);       // [.., 51,773,440)
  uint16_t* attnb = (uint16_t*)(ws + 1703936);        // alias Wt+xb (dead)
  uint16_t* zbuf  = (uint16_t*)(ws + 10092544);       // alias xb tail

  gate_v5_kernel<<<MM / 64, 1024, 0, stream>>>(x, Ws, Wd, (uint32_t*)gsel);
  pack_wt_kernel<<<dim3(16, 22), 256, 0, stream>>>(Wq, Wk, Wv, Wt);
  pack_wot_kernel<<<dim3(5, 16), 256, 0, stream>>>(Wo, WoT);
  xbf_kernel<<<(MM * DD / 4) / 256, 256, 0, stream>>>(x, xb);
  proj_mfma_kernel<<<dim3(NWT / 128, MM / 128), 256, 0, stream>>>(xb, Wt, proj);
  vbuild_kernel<<<32 * 32, 256, 0, stream>>>(proj, gsel, vt);
  flash_mfma_kernel<<<BB * HH * (TT / 128), 256, 0, stream>>>(proj, vt, attnb);
  zbuild_kernel<<<MM, 64, 0, stream>>>(attnb, (const uint32_t*)gsel, zbuf);
  out_mfma_kernel<<<dim3(DD / 128, MM / 128), 256, 0, stream>>>(zbuf, WoT, out);
}

// Round 4
// 273.118 us; speedup vs baseline: 1.4581x; 1.0011x over previous
//
#include <hip/hip_runtime.h>
#include <cstdint>
#include <cstddef>

// Problem constants
#define BB 4
#define TT 2048
#define DD 1024
#define HH 8
#define DH 64
#define EE 5
#define MM (BB*TT)          // 8192 rows
#define PLD 1344            // proj leading dim (q 512 | k 512 | xv 320)
#define NWT 1408            // padded N for MFMA proj (11 * 128)

typedef short short8 __attribute__((ext_vector_type(8)));
typedef float f32x4  __attribute__((ext_vector_type(4)));

// ---------- bf16 helpers ----------
__device__ __forceinline__ float bflo(uint32_t u) { union { uint32_t i; float f; } v; v.i = u << 16; return v.f; }
__device__ __forceinline__ float bfhi(uint32_t u) { union { uint32_t i; float f; } v; v.i = u & 0xFFFF0000u; return v.f; }
__device__ __forceinline__ float bf2f(uint16_t u) { union { uint32_t i; float f; } v; v.i = ((uint32_t)u) << 16; return v.f; }
// cheap bf16 pack: round-half-up (+0x8000) then v_perm_b32 pair-pack (1 op).
// Differs from RNE only on exact ties — negligible for absmax.
__device__ __forceinline__ uint32_t pkbf(float a, float b) {
  uint32_t ua = __float_as_uint(a) + 0x8000u;
  uint32_t ub = __float_as_uint(b) + 0x8000u;
  return __builtin_amdgcn_perm(ub, ua, 0x07060302u);  // [ua.b2,ua.b3,ub.b2,ub.b3]
}
__device__ __forceinline__ uint16_t bfr1(float f) {
  return (uint16_t)((__float_as_uint(f) + 0x8000u) >> 16);
}

// ---------- async global->LDS, 16B per lane (dest = wave base + lane*16) ----------
__device__ __forceinline__ void gload16(const void* g, void* l) {
  __builtin_amdgcn_global_load_lds(
      (const __attribute__((address_space(1))) uint32_t*)g,
      (__attribute__((address_space(3))) uint32_t*)l, 16, 0, 0);
}

// ---------- pack W^T bf16 [NWT][1024] for MFMA proj (LDS tile transpose) ----------
__global__ __launch_bounds__(256) void pack_wt_kernel(
    const float* __restrict__ Wq, const float* __restrict__ Wk,
    const float* __restrict__ Wv, uint16_t* __restrict__ Wt)
{
  __shared__ __align__(16) uint16_t Ts[64 * 68];
  int k0 = blockIdx.x * 64, n0 = blockIdx.y * 64;
  int t = threadIdx.x;
#pragma unroll
  for (int rep = 0; rep < 16; ++rep) {
    int li = rep * 256 + t;
    int kl = li >> 6, nl = li & 63;
    int k = k0 + kl, n = n0 + nl;
    float v = 0.f;
    if (n < 512)       v = Wq[k * 512 + n];
    else if (n < 1024) v = Wk[k * 512 + (n - 512)];
    else if (n < 1344) { int nn = n - 1024; v = Wv[((size_t)(nn >> 6) * 1024 + k) * 64 + (nn & 63)]; }
    Ts[kl * 68 + nl] = bfr1(v);
  }
  __syncthreads();
#pragma unroll
  for (int rep = 0; rep < 16; ++rep) {
    int li = rep * 256 + t;
    int nl = li >> 6, kl = li & 63;
    Wt[(size_t)(n0 + nl) * 1024 + k0 + kl] = Ts[kl * 68 + nl];
  }
}

// ---------- pack Wo[320][1024] fp32 -> WoT bf16 [1024][320] ----------
__global__ __launch_bounds__(256) void pack_wot_kernel(
    const float* __restrict__ Wo, uint16_t* __restrict__ WoT)
{
  __shared__ __align__(16) uint16_t Ts[64 * 68];
  int k0 = blockIdx.x * 64, n0 = blockIdx.y * 64;
  int t = threadIdx.x;
#pragma unroll
  for (int rep = 0; rep < 16; ++rep) {
    int li = rep * 256 + t;
    int kl = li >> 6, nl = li & 63;
    Ts[kl * 68 + nl] = bfr1(Wo[(size_t)(k0 + kl) * 1024 + n0 + nl]);
  }
  __syncthreads();
#pragma unroll
  for (int rep = 0; rep < 16; ++rep) {
    int li = rep * 256 + t;
    int nl = li >> 6, kl = li & 63;
    WoT[(size_t)(n0 + nl) * 320 + k0 + kl] = Ts[kl * 68 + nl];
  }
}

// ---------- x -> bf16 ----------
__global__ __launch_bounds__(256) void xbf_kernel(const float* __restrict__ x, uint16_t* __restrict__ xb)
{
  int i = (blockIdx.x * 256 + threadIdx.x) * 4;
  float4 v = *(const float4*)(x + i);
  uint2 o;
  o.x = pkbf(v.x, v.y);
  o.y = pkbf(v.z, v.w);
  *(uint2*)(xb + i) = o;
}

// ---------- top-2 of 5 (lax.top_k tie rule: lower index wins) ----------
__device__ __forceinline__ void top2_5(float g0, float g1, float g2, float g3, float g4,
                                       int& i1, float& b1, int& i2, float& b2) {
  i1 = 0; b1 = g0;
  if (g1 > b1) { b1 = g1; i1 = 1; }
  if (g2 > b1) { b1 = g2; i1 = 2; }
  if (g3 > b1) { b1 = g3; i1 = 3; }
  if (g4 > b1) { b1 = g4; i1 = 4; }
  i2 = -1; b2 = -__builtin_inff();
  if (i1 != 0 && g0 > b2) { b2 = g0; i2 = 0; }
  if (i1 != 1 && g1 > b2) { b2 = g1; i2 = 1; }
  if (i1 != 2 && g2 > b2) { b2 = g2; i2 = 2; }
  if (i1 != 3 && g3 > b2) { b2 = g3; i2 = 3; }
  if (i1 != 4 && g4 > b2) { b2 = g4; i2 = 4; }
}

// ---------- gate helpers: 20-wide uniform W batch + fma ----------
__device__ __forceinline__ void ldw20(float* d, const float* __restrict__ p) {
#pragma unroll
  for (int j = 0; j < 20; ++j) d[j] = p[j];
}
__device__ __forceinline__ void fma20(float* acc, const float* wv, float xv) {
#pragma unroll
  for (int j = 0; j < 20; ++j) acc[j] = fmaf(xv, wv[j], acc[j]);
}

// ---------- fused gate GEMM v5 (exact fp32, in-block 4-way K-split) ----------
// Grid 128 x 1024 threads (16 waves = 4 waves/SIMD -> SMEM latency hidden by
// wave interleave). lane = row (64 rows). Wave (cg, kq): cg = wave-uniform
// 20-col group -> W row loads are scalar s_load, ping-pong double-buffered.
// kq = in-TILE k-split (no barrier serialization). x tile LDS stride-132.
// K-partials combined in-LDS, fixed tree (s0+s1)+(s2+s3) — deterministic.
__global__ __launch_bounds__(1024) void gate_v5_kernel(
    const float* __restrict__ x, const float* __restrict__ Ws,
    const float* __restrict__ Wd, uint32_t* __restrict__ gsel32)
{
  __shared__ __align__(16) float xs[64 * 132];   // 33,792 B
  int t = threadIdx.x;
  int m0 = blockIdx.x * 64;
  int w = t >> 6, lane = t & 63;
  int cg = __builtin_amdgcn_readfirstlane(w & 3);
  int kq = __builtin_amdgcn_readfirstlane(w >> 2);
  const float* __restrict__ Wg = (cg < 2) ? Ws : Wd;
  const float* __restrict__ wbase = Wg + (size_t)(kq * 32) * 40 + (cg & 1) * 20;

  float acc[20];
#pragma unroll
  for (int j = 0; j < 20; ++j) acc[j] = 0.f;

  for (int tile = 0; tile < 8; ++tile) {
    __syncthreads();
#pragma unroll
    for (int rep = 0; rep < 2; ++rep) {
      int li = rep * 1024 + t;
      int row = li >> 5, kg = li & 31;
      float4 v = *(const float4*)&x[(size_t)(m0 + row) * 1024 + tile * 128 + kg * 4];
      *(float4*)&xs[row * 132 + kg * 4] = v;
    }
    __syncthreads();

    const float* wp = wbase + (size_t)tile * 128 * 40;
    const float* xp = &xs[lane * 132 + kq * 32];
    float wc[20], wn[20];
    ldw20(wc, wp);                       // k-local 0
#pragma unroll
    for (int k4 = 0; k4 < 8; ++k4) {
      float4 xv = *(const float4*)&xp[k4 * 4];
      ldw20(wn, wp + (size_t)(k4 * 4 + 1) * 40);
      fma20(acc, wc, xv.x);              // k = 4*k4+0
      ldw20(wc, wp + (size_t)(k4 * 4 + 2) * 40);
      fma20(acc, wn, xv.y);              // k = 4*k4+1
      ldw20(wn, wp + (size_t)(k4 * 4 + 3) * 40);
      fma20(acc, wc, xv.z);              // k = 4*k4+2
      if (k4 < 7) ldw20(wc, wp + (size_t)(k4 * 4 + 4) * 40);
      fma20(acc, wn, xv.w);              // k = 4*k4+3
    }
  }

  // ---- in-LDS K-split reduction, tree (s0+s1)+(s2+s3), slices ascending ----
  float* red = xs;                       // [cg][lane][21] = 5376 floats, fits
  int ro = cg * (64 * 21) + lane * 21;
  __syncthreads();                       // xs (x tile) dead
  if (kq == 1) {
#pragma unroll
    for (int j = 0; j < 20; ++j) red[ro + j] = acc[j];
  }
  __syncthreads();
  if (kq == 0) {
#pragma unroll
    for (int j = 0; j < 20; ++j) acc[j] += red[ro + j];   // s0+s1
  }
  __syncthreads();
  if (kq == 3) {
#pragma unroll
    for (int j = 0; j < 20; ++j) red[ro + j] = acc[j];
  }
  __syncthreads();
  if (kq == 2) {
#pragma unroll
    for (int j = 0; j < 20; ++j) acc[j] += red[ro + j];   // s2+s3
  }
  __syncthreads();
  if (kq == 2) {
#pragma unroll
    for (int j = 0; j < 20; ++j) red[ro + j] = acc[j];
  }
  __syncthreads();

  if (kq == 0) {
#pragma unroll
    for (int j = 0; j < 20; ++j) acc[j] += red[ro + j];   // (s0+s1)+(s2+s3)
    int m = m0 + lane;
    if (cg < 2) {      // Ws: V-expert selection + sigmoid weights (words 0-2)
#pragma unroll
      for (int hh = 0; hh < 4; ++hh) {
        int i1, i2; float b1, b2;
        top2_5(acc[hh * 5 + 0], acc[hh * 5 + 1], acc[hh * 5 + 2],
               acc[hh * 5 + 3], acc[hh * 5 + 4], i1, b1, i2, b2);
        float w1 = 1.f / (1.f + __expf(-b1));
        float w2 = 1.f / (1.f + __expf(-b2));
        uint32_t* g = gsel32 + ((size_t)m * 8 + (cg & 1) * 4 + hh) * 4;
        g[0] = __float_as_uint(w1);
        g[1] = __float_as_uint(w2);
        g[2] = (uint32_t)(i1 | (i2 << 3));
      }
    } else {           // Wd: out-expert selection only (word 3)
#pragma unroll
      for (int hh = 0; hh < 4; ++hh) {
        int j1, j2; float c1, c2;
        top2_5(acc[hh * 5 + 0], acc[hh * 5 + 1], acc[hh * 5 + 2],
               acc[hh * 5 + 3], acc[hh * 5 + 4], j1, c1, j2, c2);
        uint32_t* g = gsel32 + ((size_t)m * 8 + (cg & 1) * 4 + hh) * 4;
        g[3] = (uint32_t)(j1 | (j2 << 3));
      }
    }
  }
}

// ---------- proj MFMA GEMM (m97-style): global_load_lds into unpadded tiles ----------
__global__ __launch_bounds__(256) void proj_mfma_kernel(
    const uint16_t* __restrict__ xb, const uint16_t* __restrict__ Wt,
    uint16_t* __restrict__ proj)
{
  __shared__ __align__(16) uint16_t As[128 * 32];  // [m][k] unpadded (required by lds-DMA)
  __shared__ __align__(16) uint16_t Bs[128 * 32];  // [n][k]
  int t = threadIdx.x;
  int n0 = blockIdx.x * 128, m0 = blockIdx.y * 128;
  int w = t >> 6, lane = t & 63, q = lane >> 4, c = lane & 15;
  int wm = w & 1, wn = w >> 1;
  int lr = lane >> 2, lc = (lane & 3) * 8;   // 16 rows/chunk, 16B per lane
  f32x4 zf = {0.f, 0.f, 0.f, 0.f};
  f32x4 acc[4][4];
#pragma unroll
  for (int i = 0; i < 4; ++i)
#pragma unroll
    for (int j = 0; j < 4; ++j) acc[i][j] = zf;

  for (int kb = 0; kb < 32; ++kb) {
    __syncthreads();
#pragma unroll
    for (int j = 0; j < 2; ++j) {
      int row = w * 32 + j * 16 + lr;
      gload16(xb + (size_t)(m0 + row) * 1024 + kb * 32 + lc,
              &As[(w * 32 + j * 16) * 32 + lane * 8]);
      gload16(Wt + (size_t)(n0 + row) * 1024 + kb * 32 + lc,
              &Bs[(w * 32 + j * 16) * 32 + lane * 8]);
    }
    __syncthreads();
    short8 af[4], bfr[4];
#pragma unroll
    for (int i = 0; i < 4; ++i)
      af[i] = *(const short8*)&As[(wm * 64 + i * 16 + c) * 32 + q * 8];
#pragma unroll
    for (int j = 0; j < 4; ++j)
      bfr[j] = *(const short8*)&Bs[(wn * 64 + j * 16 + c) * 32 + q * 8];
#pragma unroll
    for (int i = 0; i < 4; ++i)
#pragma unroll
      for (int j = 0; j < 4; ++j)
        acc[i][j] = __builtin_amdgcn_mfma_f32_16x16x32_bf16(af[i], bfr[j], acc[i][j], 0, 0, 0);
  }
#pragma unroll
  for (int i = 0; i < 4; ++i)
#pragma unroll
    for (int j = 0; j < 4; ++j) {
      int col = n0 + wn * 64 + j * 16 + c;
      if (col < PLD) {
#pragma unroll
        for (int reg = 0; reg < 4; ++reg) {
          int row = m0 + wm * 64 + i * 16 + q * 4 + reg;
          proj[(size_t)row * PLD + col] = bfr1(acc[i][j][reg]);
        }
      }
    }
}

// ---------- out MFMA GEMM: zbuf[8192][320] @ WoT^T -> out fp32 [8192][1024] ----------
__global__ __launch_bounds__(256) void out_mfma_kernel(
    const uint16_t* __restrict__ zb, const uint16_t* __restrict__ WoT,
    float* __restrict__ out)
{
  __shared__ __align__(16) uint16_t As[128 * 32];
  __shared__ __align__(16) uint16_t Bs[128 * 32];
  int t = threadIdx.x;
  int n0 = blockIdx.x * 128, m0 = blockIdx.y * 128;
  int w = t >> 6, lane = t & 63, q = lane >> 4, c = lane & 15;
  int wm = w & 1, wn = w >> 1;
  int lr = lane >> 2, lc = (lane & 3) * 8;
  f32x4 zf = {0.f, 0.f, 0.f, 0.f};
  f32x4 acc[4][4];
#pragma unroll
  for (int i = 0; i < 4; ++i)
#pragma unroll
    for (int j = 0; j < 4; ++j) acc[i][j] = zf;

  for (int kb = 0; kb < 10; ++kb) {
    __syncthreads();
#pragma unroll
    for (int j = 0; j < 2; ++j) {
      int row = w * 32 + j * 16 + lr;
      gload16(zb + (size_t)(m0 + row) * 320 + kb * 32 + lc,
              &As[(w * 32 + j * 16) * 32 + lane * 8]);
      gload16(WoT + (size_t)(n0 + row) * 320 + kb * 32 + lc,
              &Bs[(w * 32 + j * 16) * 32 + lane * 8]);
    }
    __syncthreads();
    short8 af[4], bfr[4];
#pragma unroll
    for (int i = 0; i < 4; ++i)
      af[i] = *(const short8*)&As[(wm * 64 + i * 16 + c) * 32 + q * 8];
#pragma unroll
    for (int j = 0; j < 4; ++j)
      bfr[j] = *(const short8*)&Bs[(wn * 64 + j * 16 + c) * 32 + q * 8];
#pragma unroll
    for (int i = 0; i < 4; ++i)
#pragma unroll
      for (int j = 0; j < 4; ++j)
        acc[i][j] = __builtin_amdgcn_mfma_f32_16x16x32_bf16(af[i], bfr[j], acc[i][j], 0, 0, 0);
  }
#pragma unroll
  for (int i = 0; i < 4; ++i)
#pragma unroll
    for (int j = 0; j < 4; ++j) {
      int col = n0 + wn * 64 + j * 16 + c;
#pragma unroll
      for (int reg = 0; reg < 4; ++reg) {
        int row = m0 + wm * 64 + i * 16 + q * 4 + reg;
        out[(size_t)row * 1024 + col] = acc[i][j][reg];
      }
    }
}

// ---------- vbuild: v combine into d-major vt, cols PRE-PERMUTED (j' = (tt&15)*4+(tt>>4)) ----------
__global__ __launch_bounds__(256) void vbuild_kernel(
    const uint16_t* __restrict__ proj, const uint4* __restrict__ gsel,
    uint16_t* __restrict__ vt)
{
  int bi = blockIdx.x;            // 1024 = bh(32) x tb(32)
  int bh = bi >> 5, tb = bi & 31;
  int b = bh >> 3, h = bh & 7;
  int t = threadIdx.x;
  int tt = t & 63, dg = t >> 6;
  int m = b * 2048 + tb * 64 + tt;
  uint4 gs = gsel[m * 8 + h];
  float w1 = __uint_as_float(gs.x), w2 = __uint_as_float(gs.y);
  int i1 = gs.z & 7, i2 = (gs.z >> 3) & 7;
  const uint16_t* base = proj + (size_t)m * PLD + 1024;
  const uint4* p1 = (const uint4*)(base + i1 * 64 + dg * 16);
  const uint4* p2 = (const uint4*)(base + i2 * 64 + dg * 16);
  uint4 A0 = p1[0], A1 = p1[1], B0 = p2[0], B1 = p2[1];
  float v[16];
  v[0]  = w1*bflo(A0.x) + w2*bflo(B0.x); v[1]  = w1*bfhi(A0.x) + w2*bfhi(B0.x);
  v[2]  = w1*bflo(A0.y) + w2*bflo(B0.y); v[3]  = w1*bfhi(A0.y) + w2*bfhi(B0.y);
  v[4]  = w1*bflo(A0.z) + w2*bflo(B0.z); v[5]  = w1*bfhi(A0.z) + w2*bfhi(B0.z);
  v[6]  = w1*bflo(A0.w) + w2*bflo(B0.w); v[7]  = w1*bfhi(A0.w) + w2*bfhi(B0.w);
  v[8]  = w1*bflo(A1.x) + w2*bflo(B1.x); v[9]  = w1*bfhi(A1.x) + w2*bfhi(B1.x);
  v[10] = w1*bflo(A1.y) + w2*bflo(B1.y); v[11] = w1*bfhi(A1.y) + w2*bfhi(B1.y);
  v[12] = w1*bflo(A1.z) + w2*bflo(B1.z); v[13] = w1*bfhi(A1.z) + w2*bfhi(B1.z);
  v[14] = w1*bflo(A1.w) + w2*bflo(B1.w); v[15] = w1*bfhi(A1.w) + w2*bfhi(B1.w);
  int pcol = ((tt & 15) << 2) | (tt >> 4);
#pragma unroll
  for (int dd = 0; dd < 16; ++dd)
    vt[(size_t)(bh * 64 + dg * 16 + dd) * 2048 + tb * 64 + pcol] = bfr1(v[dd]);
}

// ---------- flash attention v2: 64-row Q tiles (grid 1024 -> 4 blocks/CU),
// Q fragments direct from global (no Qs LDS), K/V register-prefetch (T14),
// exp2 with folded scale (0.125*log2e; exact vs old path since 0.125 is an
// exponent shift), no-max softmax ----------
__global__ __launch_bounds__(256, 4) void flash_mfma_kernel(
    const uint16_t* __restrict__ proj, const uint16_t* __restrict__ vt,
    uint16_t* __restrict__ attnb)
{
  __shared__ __align__(16) uint16_t Ks[64 * 72];   // [j][d]
  __shared__ __align__(16) uint16_t Vs[64 * 72];   // [d][j']
  __shared__ __align__(16) uint16_t Ps[64 * 72];   // [r][j']
  int t = threadIdx.x;
  int bx = blockIdx.x;
  int qb = bx & 31, bh = bx >> 5;
  int h = bh & 7, b = bh >> 3;
  int w = t >> 6, lane = t & 63, q = lane >> 4, c = lane & 15;
  int srow = t >> 2, scq = t & 3;

  // Q fragments straight from proj (raw, unscaled): wave w owns q-rows
  // [w*16, w*16+16); lane holds row c, k-chunk hf*32+q*8.
  short8 aq[2];
  {
    const uint16_t* qp = proj + (size_t)(b * 2048 + qb * 64 + w * 16 + c) * PLD + h * 64;
    aq[0] = *(const short8*)(qp + q * 8);
    aq[1] = *(const short8*)(qp + 32 + q * 8);
  }

  f32x4 zf = {0.f, 0.f, 0.f, 0.f};
  f32x4 of[4];
  float ls[4];
#pragma unroll
  for (int nt = 0; nt < 4; ++nt) { of[nt] = zf; ls[nt] = 0.f; }

  // K/V register prefetch (T14): issue tile-it loads; LDS-write at top of it.
  const uint16_t* kg = proj + (size_t)(b * 2048 + srow) * PLD + 512 + h * 64 + scq * 16;
  const uint16_t* vg = vt + (size_t)(bh * 64 + srow) * 2048 + scq * 16;
  uint4 kp0, kp1, vp0, vp1;
  kp0 = ((const uint4*)kg)[0]; kp1 = ((const uint4*)kg)[1];
  vp0 = ((const uint4*)vg)[0]; vp1 = ((const uint4*)vg)[1];

  for (int it = 0; it < 32; ++it) {
    if (it) __syncthreads();             // prev compute done reading Ks/Vs
    *(uint4*)&Ks[srow * 72 + scq * 16] = kp0;
    *(uint4*)&Ks[srow * 72 + scq * 16 + 8] = kp1;
    *(uint4*)&Vs[srow * 72 + scq * 16] = vp0;
    *(uint4*)&Vs[srow * 72 + scq * 16 + 8] = vp1;
    __syncthreads();
    if (it < 31) {                       // overlap next-tile loads with compute
      const uint4* pk = (const uint4*)(kg + (size_t)(it + 1) * 64 * PLD);
      kp0 = pk[0]; kp1 = pk[1];
      const uint4* pv = (const uint4*)(vg + (it + 1) * 64);
      vp0 = pv[0]; vp1 = pv[1];
    }

    // S = Q K^T (raw scores; scale folded into exp2 arg below)
    short8 bk[4][2];
#pragma unroll
    for (int nt = 0; nt < 4; ++nt) {
      bk[nt][0] = *(const short8*)&Ks[(nt * 16 + c) * 72 + q * 8];
      bk[nt][1] = *(const short8*)&Ks[(nt * 16 + c) * 72 + 32 + q * 8];
    }
    f32x4 sf[4];
#pragma unroll
    for (int nt = 0; nt < 4; ++nt) {
      f32x4 s = __builtin_amdgcn_mfma_f32_16x16x32_bf16(aq[0], bk[nt][0], zf, 0, 0, 0);
      sf[nt] = __builtin_amdgcn_mfma_f32_16x16x32_bf16(aq[1], bk[nt][1], s, 0, 0, 0);
    }

    // p = exp2(s * 0.125*log2e); per-lane partial sums; packed b64 P write
#pragma unroll
    for (int reg = 0; reg < 4; ++reg) {
      float p0 = __builtin_amdgcn_exp2f(sf[0][reg] * 0.18033688f);
      float p1 = __builtin_amdgcn_exp2f(sf[1][reg] * 0.18033688f);
      float p2 = __builtin_amdgcn_exp2f(sf[2][reg] * 0.18033688f);
      float p3 = __builtin_amdgcn_exp2f(sf[3][reg] * 0.18033688f);
      ls[reg] += (p0 + p1) + (p2 + p3);
      uint2 pw;
      pw.x = pkbf(p0, p1);
      pw.y = pkbf(p2, p3);
      *(uint2*)&Ps[(w * 16 + q * 4 + reg) * 72 + c * 4] = pw;
    }

    // O += P V  (wave-private Ps rows; same-wave DS ops retire in order)
    short8 bv[4][2];
#pragma unroll
    for (int nt = 0; nt < 4; ++nt) {
      bv[nt][0] = *(const short8*)&Vs[(nt * 16 + c) * 72 + q * 8];
      bv[nt][1] = *(const short8*)&Vs[(nt * 16 + c) * 72 + 32 + q * 8];
    }
    short8 ap0 = *(const short8*)&Ps[(w * 16 + c) * 72 + q * 8];
    short8 ap1 = *(const short8*)&Ps[(w * 16 + c) * 72 + 32 + q * 8];
#pragma unroll
    for (int nt = 0; nt < 4; ++nt) {
      of[nt] = __builtin_amdgcn_mfma_f32_16x16x32_bf16(ap0, bv[nt][0], of[nt], 0, 0, 0);
      of[nt] = __builtin_amdgcn_mfma_f32_16x16x32_bf16(ap1, bv[nt][1], of[nt], 0, 0, 0);
    }
  }

#pragma unroll
  for (int reg = 0; reg < 4; ++reg) {
    float s = ls[reg];
    s += __shfl_xor(s, 1);
    s += __shfl_xor(s, 2);
    s += __shfl_xor(s, 4);
    s += __shfl_xor(s, 8);
    float inv = 1.0f / s;
    size_t row = (size_t)(b * 2048 + qb * 64 + w * 16 + q * 4 + reg);
#pragma unroll
    for (int nt = 0; nt < 4; ++nt)
      attnb[row * 512 + h * 64 + nt * 16 + c] = bfr1(of[nt][reg] * inv);
  }
}

// ---------- zbuild: z[m][e*64+c] = sum_h mask_o[h,e] * attn[m][h*64+c] ----------
__global__ __launch_bounds__(64) void zbuild_kernel(
    const uint16_t* __restrict__ attnb, const uint32_t* __restrict__ gselw,
    uint16_t* __restrict__ zbuf)
{
  int m = blockIdx.x; int c = threadIdx.x;
  float acc[5] = {0.f, 0.f, 0.f, 0.f, 0.f};
#pragma unroll
  for (int h = 0; h < 8; ++h) {
    uint32_t sel = gselw[(m * 8 + h) * 4 + 3];
    int e1 = sel & 7, e2 = (sel >> 3) & 7;
    float a = bf2f(attnb[(size_t)m * 512 + h * 64 + c]);
#pragma unroll
    for (int e = 0; e < 5; ++e)
      acc[e] += (e == e1 || e == e2) ? a : 0.f;
  }
#pragma unroll
  for (int e = 0; e < 5; ++e)
    zbuf[(size_t)m * 320 + e * 64 + c] = bfr1(acc[e]);
}

// ---------- launch ----------
extern "C" void kernel_launch(void* const* d_in, const int* in_sizes, int n_in,
                              void* d_out, int out_size, void* d_ws, size_t ws_size,
                              hipStream_t stream) {
  const float* x  = (const float*)d_in[0];
  const float* Wq = (const float*)d_in[1];
  const float* Wk = (const float*)d_in[2];
  const float* Ws = (const float*)d_in[3];
  const float* Wd = (const float*)d_in[4];
  const float* Wv = (const float*)d_in[5];
  const float* Wo = (const float*)d_in[6];
  float* out = (float*)d_out;

  // workspace carve, lifetime-aliased; high-water 51,773,440 B
  char* ws = (char*)d_ws;
  uint4*    gsel  = (uint4*)   (ws);                  // [0, 1,048,576)
  uint16_t* WoT   = (uint16_t*)(ws + 1048576);        // [.., 1,703,936)
  uint16_t* Wt    = (uint16_t*)(ws + 1703936);        // [.., 4,587,520)  dead after proj
  uint16_t* xb    = (uint16_t*)(ws + 4587520);        // [.., 21,364,736) dead after proj
  uint16_t* proj  = (uint16_t*)(ws + 21364736);       // [.., 43,384,832)
  uint16_t* vt    = (uint16_t*)(ws + 43384832);       // [.., 51,773,440)
  uint16_t* attnb = (uint16_t*)(ws + 1703936);        // alias Wt+xb (dead)
  uint16_t* zbuf  = (uint16_t*)(ws + 10092544);       // alias xb tail

  gate_v5_kernel<<<MM / 64, 1024, 0, stream>>>(x, Ws, Wd, (uint32_t*)gsel);
  pack_wt_kernel<<<dim3(16, 22), 256, 0, stream>>>(Wq, Wk, Wv, Wt);
  pack_wot_kernel<<<dim3(5, 16), 256, 0, stream>>>(Wo, WoT);
  xbf_kernel<<<(MM * DD / 4) / 256, 256, 0, stream>>>(x, xb);
  proj_mfma_kernel<<<dim3(NWT / 128, MM / 128), 256, 0, stream>>>(xb, Wt, proj);
  vbuild_kernel<<<32 * 32, 256, 0, stream>>>(proj, gsel, vt);
  flash_mfma_kernel<<<BB * HH * (TT / 64), 256, 0, stream>>>(proj, vt, attnb);
  zbuild_kernel<<<MM, 64, 0, stream>>>(attnb, (const uint32_t*)gsel, zbuf);
  out_mfma_kernel<<<dim3(DD / 128, MM / 128), 256, 0, stream>>>(zbuf, WoT, out);
}

// Round 5
// 253.761 us; speedup vs baseline: 1.5693x; 1.0763x over previous
//
#include <hip/hip_runtime.h>
#include <cstdint>
#include <cstddef>

// Problem constants
#define BB 4
#define TT 2048
#define DD 1024
#define HH 8
#define DH 64
#define EE 5
#define MM (BB*TT)          // 8192 rows
#define PLD 1344            // proj leading dim (q 512 | k 512 | xv 320)
#define NWT 1408            // padded N for MFMA proj (11 * 128)

typedef short short8 __attribute__((ext_vector_type(8)));
typedef float f32x4  __attribute__((ext_vector_type(4)));
typedef float f32x16 __attribute__((ext_vector_type(16)));
typedef unsigned int u32x2 __attribute__((ext_vector_type(2)));

// ---------- bf16 helpers ----------
__device__ __forceinline__ float bflo(uint32_t u) { union { uint32_t i; float f; } v; v.i = u << 16; return v.f; }
__device__ __forceinline__ float bfhi(uint32_t u) { union { uint32_t i; float f; } v; v.i = u & 0xFFFF0000u; return v.f; }
__device__ __forceinline__ float bf2f(uint16_t u) { union { uint32_t i; float f; } v; v.i = ((uint32_t)u) << 16; return v.f; }
// cheap bf16 pack: round-half-up (+0x8000) then v_perm_b32 pair-pack (1 op).
__device__ __forceinline__ uint32_t pkbf(float a, float b) {
  uint32_t ua = __float_as_uint(a) + 0x8000u;
  uint32_t ub = __float_as_uint(b) + 0x8000u;
  return __builtin_amdgcn_perm(ub, ua, 0x07060302u);  // [ua.b2,ua.b3,ub.b2,ub.b3]
}
__device__ __forceinline__ uint16_t bfr1(float f) {
  return (uint16_t)((__float_as_uint(f) + 0x8000u) >> 16);
}
// RNE pair-pack via hardware cvt (1 op); lo = a, hi = b
__device__ __forceinline__ uint32_t cvtpk(float a, float b) {
  uint32_t r;
  asm("v_cvt_pk_bf16_f32 %0, %1, %2" : "=v"(r) : "v"(a), "v"(b));
  return r;
}

// ---------- async global->LDS, 16B per lane (dest = wave base + lane*16) ----------
__device__ __forceinline__ void gload16(const void* g, void* l) {
  __builtin_amdgcn_global_load_lds(
      (const __attribute__((address_space(1))) uint32_t*)g,
      (__attribute__((address_space(3))) uint32_t*)l, 16, 0, 0);
}

// ---------- pack W^T bf16 [NWT][1024] for MFMA proj (LDS tile transpose) ----------
__global__ __launch_bounds__(256) void pack_wt_kernel(
    const float* __restrict__ Wq, const float* __restrict__ Wk,
    const float* __restrict__ Wv, uint16_t* __restrict__ Wt)
{
  __shared__ __align__(16) uint16_t Ts[64 * 68];
  int k0 = blockIdx.x * 64, n0 = blockIdx.y * 64;
  int t = threadIdx.x;
#pragma unroll
  for (int rep = 0; rep < 16; ++rep) {
    int li = rep * 256 + t;
    int kl = li >> 6, nl = li & 63;
    int k = k0 + kl, n = n0 + nl;
    float v = 0.f;
    if (n < 512)       v = Wq[k * 512 + n];
    else if (n < 1024) v = Wk[k * 512 + (n - 512)];
    else if (n < 1344) { int nn = n - 1024; v = Wv[((size_t)(nn >> 6) * 1024 + k) * 64 + (nn & 63)]; }
    Ts[kl * 68 + nl] = bfr1(v);
  }
  __syncthreads();
#pragma unroll
  for (int rep = 0; rep < 16; ++rep) {
    int li = rep * 256 + t;
    int nl = li >> 6, kl = li & 63;
    Wt[(size_t)(n0 + nl) * 1024 + k0 + kl] = Ts[kl * 68 + nl];
  }
}

// ---------- pack Wo[320][1024] fp32 -> WoT bf16 [1024][320] ----------
__global__ __launch_bounds__(256) void pack_wot_kernel(
    const float* __restrict__ Wo, uint16_t* __restrict__ WoT)
{
  __shared__ __align__(16) uint16_t Ts[64 * 68];
  int k0 = blockIdx.x * 64, n0 = blockIdx.y * 64;
  int t = threadIdx.x;
#pragma unroll
  for (int rep = 0; rep < 16; ++rep) {
    int li = rep * 256 + t;
    int kl = li >> 6, nl = li & 63;
    Ts[kl * 68 + nl] = bfr1(Wo[(size_t)(k0 + kl) * 1024 + n0 + nl]);
  }
  __syncthreads();
#pragma unroll
  for (int rep = 0; rep < 16; ++rep) {
    int li = rep * 256 + t;
    int nl = li >> 6, kl = li & 63;
    WoT[(size_t)(n0 + nl) * 320 + k0 + kl] = Ts[kl * 68 + nl];
  }
}

// ---------- x -> bf16 ----------
__global__ __launch_bounds__(256) void xbf_kernel(const float* __restrict__ x, uint16_t* __restrict__ xb)
{
  int i = (blockIdx.x * 256 + threadIdx.x) * 4;
  float4 v = *(const float4*)(x + i);
  uint2 o;
  o.x = pkbf(v.x, v.y);
  o.y = pkbf(v.z, v.w);
  *(uint2*)(xb + i) = o;
}

// ---------- top-2 of 5 (lax.top_k tie rule: lower index wins) ----------
__device__ __forceinline__ void top2_5(float g0, float g1, float g2, float g3, float g4,
                                       int& i1, float& b1, int& i2, float& b2) {
  i1 = 0; b1 = g0;
  if (g1 > b1) { b1 = g1; i1 = 1; }
  if (g2 > b1) { b1 = g2; i1 = 2; }
  if (g3 > b1) { b1 = g3; i1 = 3; }
  if (g4 > b1) { b1 = g4; i1 = 4; }
  i2 = -1; b2 = -__builtin_inff();
  if (i1 != 0 && g0 > b2) { b2 = g0; i2 = 0; }
  if (i1 != 1 && g1 > b2) { b2 = g1; i2 = 1; }
  if (i1 != 2 && g2 > b2) { b2 = g2; i2 = 2; }
  if (i1 != 3 && g3 > b2) { b2 = g3; i2 = 3; }
  if (i1 != 4 && g4 > b2) { b2 = g4; i2 = 4; }
}

// ---------- gate helpers: 20-wide uniform W batch + fma ----------
__device__ __forceinline__ void ldw20(float* d, const float* __restrict__ p) {
#pragma unroll
  for (int j = 0; j < 20; ++j) d[j] = p[j];
}
__device__ __forceinline__ void fma20(float* acc, const float* wv, float xv) {
#pragma unroll
  for (int j = 0; j < 20; ++j) acc[j] = fmaf(xv, wv[j], acc[j]);
}

// ---------- fused gate GEMM v5 (exact fp32, in-block 4-way K-split) ----------
__global__ __launch_bounds__(1024) void gate_v5_kernel(
    const float* __restrict__ x, const float* __restrict__ Ws,
    const float* __restrict__ Wd, uint32_t* __restrict__ gsel32)
{
  __shared__ __align__(16) float xs[64 * 132];   // 33,792 B
  int t = threadIdx.x;
  int m0 = blockIdx.x * 64;
  int w = t >> 6, lane = t & 63;
  int cg = __builtin_amdgcn_readfirstlane(w & 3);
  int kq = __builtin_amdgcn_readfirstlane(w >> 2);
  const float* __restrict__ Wg = (cg < 2) ? Ws : Wd;
  const float* __restrict__ wbase = Wg + (size_t)(kq * 32) * 40 + (cg & 1) * 20;

  float acc[20];
#pragma unroll
  for (int j = 0; j < 20; ++j) acc[j] = 0.f;

  for (int tile = 0; tile < 8; ++tile) {
    __syncthreads();
#pragma unroll
    for (int rep = 0; rep < 2; ++rep) {
      int li = rep * 1024 + t;
      int row = li >> 5, kg = li & 31;
      float4 v = *(const float4*)&x[(size_t)(m0 + row) * 1024 + tile * 128 + kg * 4];
      *(float4*)&xs[row * 132 + kg * 4] = v;
    }
    __syncthreads();

    const float* wp = wbase + (size_t)tile * 128 * 40;
    const float* xp = &xs[lane * 132 + kq * 32];
    float wc[20], wn[20];
    ldw20(wc, wp);                       // k-local 0
#pragma unroll
    for (int k4 = 0; k4 < 8; ++k4) {
      float4 xv = *(const float4*)&xp[k4 * 4];
      ldw20(wn, wp + (size_t)(k4 * 4 + 1) * 40);
      fma20(acc, wc, xv.x);              // k = 4*k4+0
      ldw20(wc, wp + (size_t)(k4 * 4 + 2) * 40);
      fma20(acc, wn, xv.y);              // k = 4*k4+1
      ldw20(wn, wp + (size_t)(k4 * 4 + 3) * 40);
      fma20(acc, wc, xv.z);              // k = 4*k4+2
      if (k4 < 7) ldw20(wc, wp + (size_t)(k4 * 4 + 4) * 40);
      fma20(acc, wn, xv.w);              // k = 4*k4+3
    }
  }

  // ---- in-LDS K-split reduction, tree (s0+s1)+(s2+s3), slices ascending ----
  float* red = xs;                       // [cg][lane][21] = 5376 floats, fits
  int ro = cg * (64 * 21) + lane * 21;
  __syncthreads();                       // xs (x tile) dead
  if (kq == 1) {
#pragma unroll
    for (int j = 0; j < 20; ++j) red[ro + j] = acc[j];
  }
  __syncthreads();
  if (kq == 0) {
#pragma unroll
    for (int j = 0; j < 20; ++j) acc[j] += red[ro + j];   // s0+s1
  }
  __syncthreads();
  if (kq == 3) {
#pragma unroll
    for (int j = 0; j < 20; ++j) red[ro + j] = acc[j];
  }
  __syncthreads();
  if (kq == 2) {
#pragma unroll
    for (int j = 0; j < 20; ++j) acc[j] += red[ro + j];   // s2+s3
  }
  __syncthreads();
  if (kq == 2) {
#pragma unroll
    for (int j = 0; j < 20; ++j) red[ro + j] = acc[j];
  }
  __syncthreads();

  if (kq == 0) {
#pragma unroll
    for (int j = 0; j < 20; ++j) acc[j] += red[ro + j];   // (s0+s1)+(s2+s3)
    int m = m0 + lane;
    if (cg < 2) {      // Ws: V-expert selection + sigmoid weights (words 0-2)
#pragma unroll
      for (int hh = 0; hh < 4; ++hh) {
        int i1, i2; float b1, b2;
        top2_5(acc[hh * 5 + 0], acc[hh * 5 + 1], acc[hh * 5 + 2],
               acc[hh * 5 + 3], acc[hh * 5 + 4], i1, b1, i2, b2);
        float w1 = 1.f / (1.f + __expf(-b1));
        float w2 = 1.f / (1.f + __expf(-b2));
        uint32_t* g = gsel32 + ((size_t)m * 8 + (cg & 1) * 4 + hh) * 4;
        g[0] = __float_as_uint(w1);
        g[1] = __float_as_uint(w2);
        g[2] = (uint32_t)(i1 | (i2 << 3));
      }
    } else {           // Wd: out-expert selection only (word 3)
#pragma unroll
      for (int hh = 0; hh < 4; ++hh) {
        int j1, j2; float c1, c2;
        top2_5(acc[hh * 5 + 0], acc[hh * 5 + 1], acc[hh * 5 + 2],
               acc[hh * 5 + 3], acc[hh * 5 + 4], j1, c1, j2, c2);
        uint32_t* g = gsel32 + ((size_t)m * 8 + (cg & 1) * 4 + hh) * 4;
        g[3] = (uint32_t)(j1 | (j2 << 3));
      }
    }
  }
}

// ---------- proj MFMA GEMM (m97-style): global_load_lds into unpadded tiles ----------
__global__ __launch_bounds__(256) void proj_mfma_kernel(
    const uint16_t* __restrict__ xb, const uint16_t* __restrict__ Wt,
    uint16_t* __restrict__ proj)
{
  __shared__ __align__(16) uint16_t As[128 * 32];  // [m][k] unpadded (required by lds-DMA)
  __shared__ __align__(16) uint16_t Bs[128 * 32];  // [n][k]
  int t = threadIdx.x;
  int n0 = blockIdx.x * 128, m0 = blockIdx.y * 128;
  int w = t >> 6, lane = t & 63, q = lane >> 4, c = lane & 15;
  int wm = w & 1, wn = w >> 1;
  int lr = lane >> 2, lc = (lane & 3) * 8;   // 16 rows/chunk, 16B per lane
  f32x4 zf = {0.f, 0.f, 0.f, 0.f};
  f32x4 acc[4][4];
#pragma unroll
  for (int i = 0; i < 4; ++i)
#pragma unroll
    for (int j = 0; j < 4; ++j) acc[i][j] = zf;

  for (int kb = 0; kb < 32; ++kb) {
    __syncthreads();
#pragma unroll
    for (int j = 0; j < 2; ++j) {
      int row = w * 32 + j * 16 + lr;
      gload16(xb + (size_t)(m0 + row) * 1024 + kb * 32 + lc,
              &As[(w * 32 + j * 16) * 32 + lane * 8]);
      gload16(Wt + (size_t)(n0 + row) * 1024 + kb * 32 + lc,
              &Bs[(w * 32 + j * 16) * 32 + lane * 8]);
    }
    __syncthreads();
    short8 af[4], bfr[4];
#pragma unroll
    for (int i = 0; i < 4; ++i)
      af[i] = *(const short8*)&As[(wm * 64 + i * 16 + c) * 32 + q * 8];
#pragma unroll
    for (int j = 0; j < 4; ++j)
      bfr[j] = *(const short8*)&Bs[(wn * 64 + j * 16 + c) * 32 + q * 8];
#pragma unroll
    for (int i = 0; i < 4; ++i)
#pragma unroll
      for (int j = 0; j < 4; ++j)
        acc[i][j] = __builtin_amdgcn_mfma_f32_16x16x32_bf16(af[i], bfr[j], acc[i][j], 0, 0, 0);
  }
#pragma unroll
  for (int i = 0; i < 4; ++i)
#pragma unroll
    for (int j = 0; j < 4; ++j) {
      int col = n0 + wn * 64 + j * 16 + c;
      if (col < PLD) {
#pragma unroll
        for (int reg = 0; reg < 4; ++reg) {
          int row = m0 + wm * 64 + i * 16 + q * 4 + reg;
          proj[(size_t)row * PLD + col] = bfr1(acc[i][j][reg]);
        }
      }
    }
}

// ---------- out MFMA GEMM: zbuf[8192][320] @ WoT^T -> out fp32 [8192][1024] ----------
__global__ __launch_bounds__(256) void out_mfma_kernel(
    const uint16_t* __restrict__ zb, const uint16_t* __restrict__ WoT,
    float* __restrict__ out)
{
  __shared__ __align__(16) uint16_t As[128 * 32];
  __shared__ __align__(16) uint16_t Bs[128 * 32];
  int t = threadIdx.x;
  int n0 = blockIdx.x * 128, m0 = blockIdx.y * 128;
  int w = t >> 6, lane = t & 63, q = lane >> 4, c = lane & 15;
  int wm = w & 1, wn = w >> 1;
  int lr = lane >> 2, lc = (lane & 3) * 8;
  f32x4 zf = {0.f, 0.f, 0.f, 0.f};
  f32x4 acc[4][4];
#pragma unroll
  for (int i = 0; i < 4; ++i)
#pragma unroll
    for (int j = 0; j < 4; ++j) acc[i][j] = zf;

  for (int kb = 0; kb < 10; ++kb) {
    __syncthreads();
#pragma unroll
    for (int j = 0; j < 2; ++j) {
      int row = w * 32 + j * 16 + lr;
      gload16(zb + (size_t)(m0 + row) * 320 + kb * 32 + lc,
              &As[(w * 32 + j * 16) * 32 + lane * 8]);
      gload16(WoT + (size_t)(n0 + row) * 320 + kb * 32 + lc,
              &Bs[(w * 32 + j * 16) * 32 + lane * 8]);
    }
    __syncthreads();
    short8 af[4], bfr[4];
#pragma unroll
    for (int i = 0; i < 4; ++i)
      af[i] = *(const short8*)&As[(wm * 64 + i * 16 + c) * 32 + q * 8];
#pragma unroll
    for (int j = 0; j < 4; ++j)
      bfr[j] = *(const short8*)&Bs[(wn * 64 + j * 16 + c) * 32 + q * 8];
#pragma unroll
    for (int i = 0; i < 4; ++i)
#pragma unroll
      for (int j = 0; j < 4; ++j)
        acc[i][j] = __builtin_amdgcn_mfma_f32_16x16x32_bf16(af[i], bfr[j], acc[i][j], 0, 0, 0);
  }
#pragma unroll
  for (int i = 0; i < 4; ++i)
#pragma unroll
    for (int j = 0; j < 4; ++j) {
      int col = n0 + wn * 64 + j * 16 + c;
#pragma unroll
      for (int reg = 0; reg < 4; ++reg) {
        int row = m0 + wm * 64 + i * 16 + q * 4 + reg;
        out[(size_t)row * 1024 + col] = acc[i][j][reg];
      }
    }
}

// ---------- vbuild: v combine into d-major vt, TRUE j order (32x32 flash
// consumes V[j][d] via B-frag k = contiguous j) ----------
__global__ __launch_bounds__(256) void vbuild_kernel(
    const uint16_t* __restrict__ proj, const uint4* __restrict__ gsel,
    uint16_t* __restrict__ vt)
{
  int bi = blockIdx.x;            // 1024 = bh(32) x tb(32)
  int bh = bi >> 5, tb = bi & 31;
  int b = bh >> 3, h = bh & 7;
  int t = threadIdx.x;
  int tt = t & 63, dg = t >> 6;
  int m = b * 2048 + tb * 64 + tt;
  uint4 gs = gsel[m * 8 + h];
  float w1 = __uint_as_float(gs.x), w2 = __uint_as_float(gs.y);
  int i1 = gs.z & 7, i2 = (gs.z >> 3) & 7;
  const uint16_t* base = proj + (size_t)m * PLD + 1024;
  const uint4* p1 = (const uint4*)(base + i1 * 64 + dg * 16);
  const uint4* p2 = (const uint4*)(base + i2 * 64 + dg * 16);
  uint4 A0 = p1[0], A1 = p1[1], B0 = p2[0], B1 = p2[1];
  float v[16];
  v[0]  = w1*bflo(A0.x) + w2*bflo(B0.x); v[1]  = w1*bfhi(A0.x) + w2*bfhi(B0.x);
  v[2]  = w1*bflo(A0.y) + w2*bflo(B0.y); v[3]  = w1*bfhi(A0.y) + w2*bfhi(B0.y);
  v[4]  = w1*bflo(A0.z) + w2*bflo(B0.z); v[5]  = w1*bfhi(A0.z) + w2*bfhi(B0.z);
  v[6]  = w1*bflo(A0.w) + w2*bflo(B0.w); v[7]  = w1*bfhi(A0.w) + w2*bfhi(B0.w);
  v[8]  = w1*bflo(A1.x) + w2*bflo(B1.x); v[9]  = w1*bfhi(A1.x) + w2*bfhi(B1.x);
  v[10] = w1*bflo(A1.y) + w2*bflo(B1.y); v[11] = w1*bfhi(A1.y) + w2*bfhi(B1.y);
  v[12] = w1*bflo(A1.z) + w2*bflo(B1.z); v[13] = w1*bfhi(A1.z) + w2*bfhi(B1.z);
  v[14] = w1*bflo(A1.w) + w2*bflo(B1.w); v[15] = w1*bfhi(A1.w) + w2*bfhi(B1.w);
#pragma unroll
  for (int dd = 0; dd < 16; ++dd)
    vt[(size_t)(bh * 64 + dg * 16 + dd) * 2048 + tb * 64 + tt] = bfr1(v[dd]);
}

// ---------- flash attention v3: 32x32x16 MFMA, swapped QK^T (S^T: q-row
// lane-local), in-register P via cvt_pk + permlane32_swap (T12), no Ps LDS,
// Q in regs, K/V register-prefetch, no-max softmax with folded 0.125 scale.
// Block = 128 q-rows x 4 waves (32 rows each); 32 KV-iterations of 64. ----------
__global__ __launch_bounds__(256) void flash_mfma_kernel(
    const uint16_t* __restrict__ proj, const uint16_t* __restrict__ vt,
    uint16_t* __restrict__ attnb)
{
  __shared__ __align__(16) uint16_t Ks[64 * 72];   // [j][d]
  __shared__ __align__(16) uint16_t Vs[64 * 72];   // [d][j] true-j order
  __shared__ float lsb[4 * 32];                    // per-wave 1/rowsum
  int t = threadIdx.x;
  int bx = blockIdx.x;
  int qb = bx & 15, bh = bx >> 4;
  int h = bh & 7, b = bh >> 3;
  int w = t >> 6, lane = t & 63;
  int r31 = lane & 31, hi = lane >> 5;
  int srow = t >> 2, scq = t & 3;

  // Q B-fragments (persist): B[k=d][n=r]: lane holds q-row r31 of this wave's
  // 32-row group, d = hi*8 + {0..7} + 16*f.
  short8 qf[4];
  {
    const uint16_t* qp = proj + (size_t)(b * 2048 + qb * 128 + w * 32 + r31) * PLD + h * 64 + hi * 8;
#pragma unroll
    for (int f = 0; f < 4; ++f) qf[f] = *(const short8*)(qp + 16 * f);
  }

  f32x16 o0 = {0.f}, o1 = {0.f};
#pragma unroll
  for (int i = 0; i < 16; ++i) { o0[i] = 0.f; o1[i] = 0.f; }
  float lsacc = 0.f;

  // K/V register prefetch: issue tile-it loads; LDS-write at top of it.
  const uint16_t* kg = proj + (size_t)(b * 2048 + srow) * PLD + 512 + h * 64 + scq * 16;
  const uint16_t* vg = vt + (size_t)(bh * 64 + srow) * 2048 + scq * 16;
  uint4 kp0, kp1, vp0, vp1;
  kp0 = ((const uint4*)kg)[0]; kp1 = ((const uint4*)kg)[1];
  vp0 = ((const uint4*)vg)[0]; vp1 = ((const uint4*)vg)[1];

  for (int it = 0; it < 32; ++it) {
    if (it) __syncthreads();             // prev compute done reading Ks/Vs
    *(uint4*)&Ks[srow * 72 + scq * 16] = kp0;
    *(uint4*)&Ks[srow * 72 + scq * 16 + 8] = kp1;
    *(uint4*)&Vs[srow * 72 + scq * 16] = vp0;
    *(uint4*)&Vs[srow * 72 + scq * 16 + 8] = vp1;
    __syncthreads();
    if (it < 31) {                       // overlap next-tile loads with compute
      const uint4* pk = (const uint4*)(kg + (size_t)(it + 1) * 64 * PLD);
      kp0 = pk[0]; kp1 = pk[1];
      const uint4* pv = (const uint4*)(vg + (it + 1) * 64);
      vp0 = pv[0]; vp1 = pv[1];
    }

    // Per j-group (32 K-rows): S^T = mfma(A=K, B=Q); C col = r (lane-local
    // q-row), C row j = (reg&3) + 8*(reg>>2) + 4*hi. Then P in-register.
    short8 pa[4];
#pragma unroll
    for (int jg = 0; jg < 2; ++jg) {
      f32x16 s;
#pragma unroll
      for (int i = 0; i < 16; ++i) s[i] = 0.f;
#pragma unroll
      for (int f = 0; f < 4; ++f) {
        short8 kf = *(const short8*)&Ks[(jg * 32 + r31) * 72 + hi * 8 + 16 * f];
        s = __builtin_amdgcn_mfma_f32_32x32x16_bf16(kf, qf[f], s, 0, 0, 0);
      }
      float p[16];
#pragma unroll
      for (int reg = 0; reg < 16; ++reg)
        p[reg] = __builtin_amdgcn_exp2f(s[reg] * 0.18033688f);
      lsacc += (((p[0] + p[1]) + (p[2] + p[3])) + ((p[4] + p[5]) + (p[6] + p[7])))
             + (((p[8] + p[9]) + (p[10] + p[11])) + ((p[12] + p[13]) + (p[14] + p[15])));
      // cvt_pk adjacent-j pairs, then permlane32_swap to assemble PV A-frags
      uint32_t X1 = cvtpk(p[0], p[1]),  X2 = cvtpk(p[2], p[3]);
      uint32_t Y1 = cvtpk(p[4], p[5]),  Y2 = cvtpk(p[6], p[7]);
      uint32_t Z1 = cvtpk(p[8], p[9]),  Z2 = cvtpk(p[10], p[11]);
      uint32_t W1 = cvtpk(p[12], p[13]), W2 = cvtpk(p[14], p[15]);
      u32x2 s1 = __builtin_amdgcn_permlane32_swap(X1, Y1, false, false);
      u32x2 s2 = __builtin_amdgcn_permlane32_swap(X2, Y2, false, false);
      u32x2 s3 = __builtin_amdgcn_permlane32_swap(Z1, W1, false, false);
      u32x2 s4 = __builtin_amdgcn_permlane32_swap(Z2, W2, false, false);
      uint4 f0 = { s1.x, s2.x, s1.y, s2.y };   // j = jg*32 + hi*8 + 0..7
      uint4 f1 = { s3.x, s4.x, s3.y, s4.y };   // j = jg*32 + 16 + hi*8 + 0..7
      pa[jg * 2 + 0] = *(short8*)&f0;
      pa[jg * 2 + 1] = *(short8*)&f1;
    }

    // O += P V : per d-tile, 4 mfma over j=64; B=V from d-major Vs (true j).
#pragma unroll
    for (int f = 0; f < 4; ++f) {
      short8 vf0 = *(const short8*)&Vs[(r31) * 72 + hi * 8 + 16 * f];
      short8 vf1 = *(const short8*)&Vs[(32 + r31) * 72 + hi * 8 + 16 * f];
      o0 = __builtin_amdgcn_mfma_f32_32x32x16_bf16(pa[f], vf0, o0, 0, 0, 0);
      o1 = __builtin_amdgcn_mfma_f32_32x32x16_bf16(pa[f], vf1, o1, 0, 0, 0);
    }
  }

  // row sums: lane-local partial + partner half; broadcast 1/ls via wave-
  // private LDS (same-wave DS ordering, no barrier needed).
  float lsc = lsacc + __shfl_xor(lsacc, 32);
  if (lane < 32) lsb[w * 32 + r31] = 1.0f / lsc;
#pragma unroll
  for (int reg = 0; reg < 16; ++reg) {
    int r = (reg & 3) + 8 * (reg >> 2) + 4 * hi;
    float inv = lsb[w * 32 + r];
    size_t row = (size_t)(b * 2048 + qb * 128 + w * 32 + r);
    attnb[row * 512 + h * 64 + r31]      = bfr1(o0[reg] * inv);
    attnb[row * 512 + h * 64 + 32 + r31] = bfr1(o1[reg] * inv);
  }
}

// ---------- zbuild: z[m][e*64+c] = sum_h mask_o[h,e] * attn[m][h*64+c] ----------
__global__ __launch_bounds__(64) void zbuild_kernel(
    const uint16_t* __restrict__ attnb, const uint32_t* __restrict__ gselw,
    uint16_t* __restrict__ zbuf)
{
  int m = blockIdx.x; int c = threadIdx.x;
  float acc[5] = {0.f, 0.f, 0.f, 0.f, 0.f};
#pragma unroll
  for (int h = 0; h < 8; ++h) {
    uint32_t sel = gselw[(m * 8 + h) * 4 + 3];
    int e1 = sel & 7, e2 = (sel >> 3) & 7;
    float a = bf2f(attnb[(size_t)m * 512 + h * 64 + c]);
#pragma unroll
    for (int e = 0; e < 5; ++e)
      acc[e] += (e == e1 || e == e2) ? a : 0.f;
  }
#pragma unroll
  for (int e = 0; e < 5; ++e)
    zbuf[(size_t)m * 320 + e * 64 + c] = bfr1(acc[e]);
}

// ---------- launch ----------
extern "C" void kernel_launch(void* const* d_in, const int* in_sizes, int n_in,
                              void* d_out, int out_size, void* d_ws, size_t ws_size,
                              hipStream_t stream) {
  const float* x  = (const float*)d_in[0];
  const float* Wq = (const float*)d_in[1];
  const float* Wk = (const float*)d_in[2];
  const float* Ws = (const float*)d_in[3];
  const float* Wd = (const float*)d_in[4];
  const float* Wv = (const float*)d_in[5];
  const float* Wo = (const float*)d_in[6];
  float* out = (float*)d_out;

  // workspace carve, lifetime-aliased; high-water 51,773,440 B
  char* ws = (char*)d_ws;
  uint4*    gsel  = (uint4*)   (ws);                  // [0, 1,048,576)
  uint16_t* WoT   = (uint16_t*)(ws + 1048576);        // [.., 1,703,936)
  uint16_t* Wt    = (uint16_t*)(ws + 1703936);        // [.., 4,587,520)  dead after proj
  uint16_t* xb    = (uint16_t*)(ws + 4587520);        // [.., 21,364,736) dead after proj
  uint16_t* proj  = (uint16_t*)(ws + 21364736);       // [.., 43,384,832)
  uint16_t* vt    = (uint16_t*)(ws + 43384832);       // [.., 51,773,440)
  uint16_t* attnb = (uint16_t*)(ws + 1703936);        // alias Wt+xb (dead)
  uint16_t* zbuf  = (uint16_t*)(ws + 10092544);       // alias xb tail

  gate_v5_kernel<<<MM / 64, 1024, 0, stream>>>(x, Ws, Wd, (uint32_t*)gsel);
  pack_wt_kernel<<<dim3(16, 22), 256, 0, stream>>>(Wq, Wk, Wv, Wt);
  pack_wot_kernel<<<dim3(5, 16), 256, 0, stream>>>(Wo, WoT);
  xbf_kernel<<<(MM * DD / 4) / 256, 256, 0, stream>>>(x, xb);
  proj_mfma_kernel<<<dim3(NWT / 128, MM / 128), 256, 0, stream>>>(xb, Wt, proj);
  vbuild_kernel<<<32 * 32, 256, 0, stream>>>(proj, gsel, vt);
  flash_mfma_kernel<<<BB * HH * (TT / 128), 256, 0, stream>>>(proj, vt, attnb);
  zbuild_kernel<<<MM, 64, 0, stream>>>(attnb, (const uint32_t*)gsel, zbuf);
  out_mfma_kernel<<<dim3(DD / 128, MM / 128), 256, 0, stream>>>(zbuf, WoT, out);
}

// Round 6
// 239.656 us; speedup vs baseline: 1.6617x; 1.0589x over previous
//
#include <hip/hip_runtime.h>
#include <cstdint>
#include <cstddef>

// Problem constants
#define BB 4
#define TT 2048
#define DD 1024
#define HH 8
#define DH 64
#define EE 5
#define MM (BB*TT)          // 8192 rows
#define PLD 1344            // proj leading dim (q 512 | k 512 | xv 320)
#define NWT 1408            // padded N for MFMA proj (11 * 128)

typedef short short8 __attribute__((ext_vector_type(8)));
typedef float f32x4  __attribute__((ext_vector_type(4)));
typedef float f32x16 __attribute__((ext_vector_type(16)));
typedef unsigned int u32x2 __attribute__((ext_vector_type(2)));

// ---------- bf16 helpers ----------
__device__ __forceinline__ float bflo(uint32_t u) { union { uint32_t i; float f; } v; v.i = u << 16; return v.f; }
__device__ __forceinline__ float bfhi(uint32_t u) { union { uint32_t i; float f; } v; v.i = u & 0xFFFF0000u; return v.f; }
__device__ __forceinline__ float bf2f(uint16_t u) { union { uint32_t i; float f; } v; v.i = ((uint32_t)u) << 16; return v.f; }
// cheap bf16 pack: round-half-up (+0x8000) then v_perm_b32 pair-pack (1 op).
__device__ __forceinline__ uint32_t pkbf(float a, float b) {
  uint32_t ua = __float_as_uint(a) + 0x8000u;
  uint32_t ub = __float_as_uint(b) + 0x8000u;
  return __builtin_amdgcn_perm(ub, ua, 0x07060302u);  // [ua.b2,ua.b3,ub.b2,ub.b3]
}
__device__ __forceinline__ uint16_t bfr1(float f) {
  return (uint16_t)((__float_as_uint(f) + 0x8000u) >> 16);
}
// RNE pair-pack via hardware cvt (1 op); lo = a, hi = b
__device__ __forceinline__ uint32_t cvtpk(float a, float b) {
  uint32_t r;
  asm("v_cvt_pk_bf16_f32 %0, %1, %2" : "=v"(r) : "v"(a), "v"(b));
  return r;
}

// ---------- async global->LDS, 16B per lane (dest = wave base + lane*16) ----------
__device__ __forceinline__ void gload16(const void* g, void* l) {
  __builtin_amdgcn_global_load_lds(
      (const __attribute__((address_space(1))) uint32_t*)g,
      (__attribute__((address_space(3))) uint32_t*)l, 16, 0, 0);
}

// ---------- pack W^T bf16 [NWT][1024] for MFMA proj (LDS tile transpose) ----------
__global__ __launch_bounds__(256) void pack_wt_kernel(
    const float* __restrict__ Wq, const float* __restrict__ Wk,
    const float* __restrict__ Wv, uint16_t* __restrict__ Wt)
{
  __shared__ __align__(16) uint16_t Ts[64 * 68];
  int k0 = blockIdx.x * 64, n0 = blockIdx.y * 64;
  int t = threadIdx.x;
#pragma unroll
  for (int rep = 0; rep < 16; ++rep) {
    int li = rep * 256 + t;
    int kl = li >> 6, nl = li & 63;
    int k = k0 + kl, n = n0 + nl;
    float v = 0.f;
    if (n < 512)       v = Wq[k * 512 + n];
    else if (n < 1024) v = Wk[k * 512 + (n - 512)];
    else if (n < 1344) { int nn = n - 1024; v = Wv[((size_t)(nn >> 6) * 1024 + k) * 64 + (nn & 63)]; }
    Ts[kl * 68 + nl] = bfr1(v);
  }
  __syncthreads();
#pragma unroll
  for (int rep = 0; rep < 16; ++rep) {
    int li = rep * 256 + t;
    int nl = li >> 6, kl = li & 63;
    Wt[(size_t)(n0 + nl) * 1024 + k0 + kl] = Ts[kl * 68 + nl];
  }
}

// ---------- pack Wo[320][1024] fp32 -> WoT bf16 [1024][320] ----------
__global__ __launch_bounds__(256) void pack_wot_kernel(
    const float* __restrict__ Wo, uint16_t* __restrict__ WoT)
{
  __shared__ __align__(16) uint16_t Ts[64 * 68];
  int k0 = blockIdx.x * 64, n0 = blockIdx.y * 64;
  int t = threadIdx.x;
#pragma unroll
  for (int rep = 0; rep < 16; ++rep) {
    int li = rep * 256 + t;
    int kl = li >> 6, nl = li & 63;
    Ts[kl * 68 + nl] = bfr1(Wo[(size_t)(k0 + kl) * 1024 + n0 + nl]);
  }
  __syncthreads();
#pragma unroll
  for (int rep = 0; rep < 16; ++rep) {
    int li = rep * 256 + t;
    int nl = li >> 6, kl = li & 63;
    WoT[(size_t)(n0 + nl) * 320 + k0 + kl] = Ts[kl * 68 + nl];
  }
}

// ---------- x -> bf16 ----------
__global__ __launch_bounds__(256) void xbf_kernel(const float* __restrict__ x, uint16_t* __restrict__ xb)
{
  int i = (blockIdx.x * 256 + threadIdx.x) * 4;
  float4 v = *(const float4*)(x + i);
  uint2 o;
  o.x = pkbf(v.x, v.y);
  o.y = pkbf(v.z, v.w);
  *(uint2*)(xb + i) = o;
}

// ---------- top-2 of 5 (lax.top_k tie rule: lower index wins) ----------
__device__ __forceinline__ void top2_5(float g0, float g1, float g2, float g3, float g4,
                                       int& i1, float& b1, int& i2, float& b2) {
  i1 = 0; b1 = g0;
  if (g1 > b1) { b1 = g1; i1 = 1; }
  if (g2 > b1) { b1 = g2; i1 = 2; }
  if (g3 > b1) { b1 = g3; i1 = 3; }
  if (g4 > b1) { b1 = g4; i1 = 4; }
  i2 = -1; b2 = -__builtin_inff();
  if (i1 != 0 && g0 > b2) { b2 = g0; i2 = 0; }
  if (i1 != 1 && g1 > b2) { b2 = g1; i2 = 1; }
  if (i1 != 2 && g2 > b2) { b2 = g2; i2 = 2; }
  if (i1 != 3 && g3 > b2) { b2 = g3; i2 = 3; }
  if (i1 != 4 && g4 > b2) { b2 = g4; i2 = 4; }
}

// ---------- gate helpers: 20-wide uniform W batch + fma ----------
__device__ __forceinline__ void ldw20(float* d, const float* __restrict__ p) {
#pragma unroll
  for (int j = 0; j < 20; ++j) d[j] = p[j];
}
__device__ __forceinline__ void fma20(float* acc, const float* wv, float xv) {
#pragma unroll
  for (int j = 0; j < 20; ++j) acc[j] = fmaf(xv, wv[j], acc[j]);
}

// ---------- fused gate GEMM v6 (exact fp32, 8-way in-tile K-split, Ws/Wd
// split across blockIdx.y) ----------
// Grid dim3(128,2) x 1024 threads: y=0 -> Ws, y=1 -> Wd. Paired blocks (x,0)
// and (x,1) have linear ids x and x+128 (both = x mod 8) -> same XCD, shared
// L2 for the duplicated x tile. Wave (cg, kq): cg in 0..1 = 20-col group
// (scalar s_load W, ping-pong), kq in 0..7 = in-tile k-split (16 k each).
// Per-wave FMA = 2560 (was 20480 in v5). K-partials combined in-LDS, fixed
// 3-round tree ((s0+s1)+(s2+s3))+((s4+s5)+(s6+s7)), stride 21 (2-way alias).
// Ws blocks write gsel words 0-2, Wd blocks word 3 (disjoint dwords).
__global__ __launch_bounds__(1024) void gate_v6_kernel(
    const float* __restrict__ x, const float* __restrict__ Ws,
    const float* __restrict__ Wd, uint32_t* __restrict__ gsel32)
{
  __shared__ __align__(16) float xs[10752];   // 43,008 B; tiles use 64*132=8448
  int t = threadIdx.x;
  int m0 = blockIdx.x * 64;
  int g  = blockIdx.y;                         // 0 = Ws, 1 = Wd
  int w = t >> 6, lane = t & 63;
  int cg = __builtin_amdgcn_readfirstlane(w & 1);
  int kq = __builtin_amdgcn_readfirstlane(w >> 1);
  const float* __restrict__ Wg = g ? Wd : Ws;
  const float* __restrict__ wbase = Wg + (size_t)(kq * 16) * 40 + cg * 20;

  float acc[20];
#pragma unroll
  for (int j = 0; j < 20; ++j) acc[j] = 0.f;

  for (int tile = 0; tile < 8; ++tile) {
    __syncthreads();
    // stage x tile 64 rows x 128 k: float4 coalesced global, float4 LDS stores
#pragma unroll
    for (int rep = 0; rep < 2; ++rep) {
      int li = rep * 1024 + t;
      int row = li >> 5, kg = li & 31;
      float4 v = *(const float4*)&x[(size_t)(m0 + row) * 1024 + tile * 128 + kg * 4];
      *(float4*)&xs[row * 132 + kg * 4] = v;
    }
    __syncthreads();

    const float* wp = wbase + (size_t)tile * 128 * 40;
    const float* xp = &xs[lane * 132 + kq * 16];
    float wc[20], wn[20];
    ldw20(wc, wp);                       // k-local 0
#pragma unroll
    for (int k4 = 0; k4 < 4; ++k4) {     // 16 k per wave per tile
      float4 xv = *(const float4*)&xp[k4 * 4];
      ldw20(wn, wp + (size_t)(k4 * 4 + 1) * 40);
      fma20(acc, wc, xv.x);              // k = 4*k4+0
      ldw20(wc, wp + (size_t)(k4 * 4 + 2) * 40);
      fma20(acc, wn, xv.y);              // k = 4*k4+1
      ldw20(wn, wp + (size_t)(k4 * 4 + 3) * 40);
      fma20(acc, wc, xv.z);              // k = 4*k4+2
      if (k4 < 3) ldw20(wc, wp + (size_t)(k4 * 4 + 4) * 40);
      fma20(acc, wn, xv.w);              // k = 4*k4+3
    }
  }

  // ---- in-LDS 8-way K-split reduction, fixed tree, stride 21 ----
  float* red = xs;                       // reuse; 4 slots x 2 cg x 64 x 21
  __syncthreads();                       // xs (x tile) dead
  if (kq & 1) {                          // round 1 writers: kq 1,3,5,7
    int ro = (((kq >> 1) * 2 + cg) * 64 + lane) * 21;
#pragma unroll
    for (int j = 0; j < 20; ++j) red[ro + j] = acc[j];
  }
  __syncthreads();
  if (!(kq & 1)) {                       // round 1 readers: kq 0,2,4,6
    int ro = (((kq >> 1) * 2 + cg) * 64 + lane) * 21;
#pragma unroll
    for (int j = 0; j < 20; ++j) acc[j] += red[ro + j];
  }
  __syncthreads();
  if (kq == 2 || kq == 6) {              // round 2 writers
    int ro = (((kq >> 2) * 2 + cg) * 64 + lane) * 21;
#pragma unroll
    for (int j = 0; j < 20; ++j) red[ro + j] = acc[j];
  }
  __syncthreads();
  if (kq == 0 || kq == 4) {              // round 2 readers
    int ro = (((kq >> 2) * 2 + cg) * 64 + lane) * 21;
#pragma unroll
    for (int j = 0; j < 20; ++j) acc[j] += red[ro + j];
  }
  __syncthreads();
  if (kq == 4) {                         // round 3 writer
    int ro = (cg * 64 + lane) * 21;
#pragma unroll
    for (int j = 0; j < 20; ++j) red[ro + j] = acc[j];
  }
  __syncthreads();

  if (kq == 0) {
    int ro = (cg * 64 + lane) * 21;
#pragma unroll
    for (int j = 0; j < 20; ++j) acc[j] += red[ro + j];   // full sum
    int m = m0 + lane;
    if (g == 0) {      // Ws: V-expert selection + sigmoid weights (words 0-2)
#pragma unroll
      for (int hh = 0; hh < 4; ++hh) {
        int i1, i2; float b1, b2;
        top2_5(acc[hh * 5 + 0], acc[hh * 5 + 1], acc[hh * 5 + 2],
               acc[hh * 5 + 3], acc[hh * 5 + 4], i1, b1, i2, b2);
        float w1 = 1.f / (1.f + __expf(-b1));
        float w2 = 1.f / (1.f + __expf(-b2));
        uint32_t* gp = gsel32 + ((size_t)m * 8 + cg * 4 + hh) * 4;
        gp[0] = __float_as_uint(w1);
        gp[1] = __float_as_uint(w2);
        gp[2] = (uint32_t)(i1 | (i2 << 3));
      }
    } else {           // Wd: out-expert selection only (word 3)
#pragma unroll
      for (int hh = 0; hh < 4; ++hh) {
        int j1, j2; float c1, c2;
        top2_5(acc[hh * 5 + 0], acc[hh * 5 + 1], acc[hh * 5 + 2],
               acc[hh * 5 + 3], acc[hh * 5 + 4], j1, c1, j2, c2);
        uint32_t* gp = gsel32 + ((size_t)m * 8 + cg * 4 + hh) * 4;
        gp[3] = (uint32_t)(j1 | (j2 << 3));
      }
    }
  }
}

// ---------- proj MFMA GEMM (m97-style): global_load_lds into unpadded tiles ----------
__global__ __launch_bounds__(256) void proj_mfma_kernel(
    const uint16_t* __restrict__ xb, const uint16_t* __restrict__ Wt,
    uint16_t* __restrict__ proj)
{
  __shared__ __align__(16) uint16_t As[128 * 32];  // [m][k] unpadded (required by lds-DMA)
  __shared__ __align__(16) uint16_t Bs[128 * 32];  // [n][k]
  int t = threadIdx.x;
  int n0 = blockIdx.x * 128, m0 = blockIdx.y * 128;
  int w = t >> 6, lane = t & 63, q = lane >> 4, c = lane & 15;
  int wm = w & 1, wn = w >> 1;
  int lr = lane >> 2, lc = (lane & 3) * 8;   // 16 rows/chunk, 16B per lane
  f32x4 zf = {0.f, 0.f, 0.f, 0.f};
  f32x4 acc[4][4];
#pragma unroll
  for (int i = 0; i < 4; ++i)
#pragma unroll
    for (int j = 0; j < 4; ++j) acc[i][j] = zf;

  for (int kb = 0; kb < 32; ++kb) {
    __syncthreads();
#pragma unroll
    for (int j = 0; j < 2; ++j) {
      int row = w * 32 + j * 16 + lr;
      gload16(xb + (size_t)(m0 + row) * 1024 + kb * 32 + lc,
              &As[(w * 32 + j * 16) * 32 + lane * 8]);
      gload16(Wt + (size_t)(n0 + row) * 1024 + kb * 32 + lc,
              &Bs[(w * 32 + j * 16) * 32 + lane * 8]);
    }
    __syncthreads();
    short8 af[4], bfr[4];
#pragma unroll
    for (int i = 0; i < 4; ++i)
      af[i] = *(const short8*)&As[(wm * 64 + i * 16 + c) * 32 + q * 8];
#pragma unroll
    for (int j = 0; j < 4; ++j)
      bfr[j] = *(const short8*)&Bs[(wn * 64 + j * 16 + c) * 32 + q * 8];
#pragma unroll
    for (int i = 0; i < 4; ++i)
#pragma unroll
      for (int j = 0; j < 4; ++j)
        acc[i][j] = __builtin_amdgcn_mfma_f32_16x16x32_bf16(af[i], bfr[j], acc[i][j], 0, 0, 0);
  }
#pragma unroll
  for (int i = 0; i < 4; ++i)
#pragma unroll
    for (int j = 0; j < 4; ++j) {
      int col = n0 + wn * 64 + j * 16 + c;
      if (col < PLD) {
#pragma unroll
        for (int reg = 0; reg < 4; ++reg) {
          int row = m0 + wm * 64 + i * 16 + q * 4 + reg;
          proj[(size_t)row * PLD + col] = bfr1(acc[i][j][reg]);
        }
      }
    }
}

// ---------- out MFMA GEMM: zbuf[8192][320] @ WoT^T -> out fp32 [8192][1024] ----------
__global__ __launch_bounds__(256) void out_mfma_kernel(
    const uint16_t* __restrict__ zb, const uint16_t* __restrict__ WoT,
    float* __restrict__ out)
{
  __shared__ __align__(16) uint16_t As[128 * 32];
  __shared__ __align__(16) uint16_t Bs[128 * 32];
  int t = threadIdx.x;
  int n0 = blockIdx.x * 128, m0 = blockIdx.y * 128;
  int w = t >> 6, lane = t & 63, q = lane >> 4, c = lane & 15;
  int wm = w & 1, wn = w >> 1;
  int lr = lane >> 2, lc = (lane & 3) * 8;
  f32x4 zf = {0.f, 0.f, 0.f, 0.f};
  f32x4 acc[4][4];
#pragma unroll
  for (int i = 0; i < 4; ++i)
#pragma unroll
    for (int j = 0; j < 4; ++j) acc[i][j] = zf;

  for (int kb = 0; kb < 10; ++kb) {
    __syncthreads();
#pragma unroll
    for (int j = 0; j < 2; ++j) {
      int row = w * 32 + j * 16 + lr;
      gload16(zb + (size_t)(m0 + row) * 320 + kb * 32 + lc,
              &As[(w * 32 + j * 16) * 32 + lane * 8]);
      gload16(WoT + (size_t)(n0 + row) * 320 + kb * 32 + lc,
              &Bs[(w * 32 + j * 16) * 32 + lane * 8]);
    }
    __syncthreads();
    short8 af[4], bfr[4];
#pragma unroll
    for (int i = 0; i < 4; ++i)
      af[i] = *(const short8*)&As[(wm * 64 + i * 16 + c) * 32 + q * 8];
#pragma unroll
    for (int j = 0; j < 4; ++j)
      bfr[j] = *(const short8*)&Bs[(wn * 64 + j * 16 + c) * 32 + q * 8];
#pragma unroll
    for (int i = 0; i < 4; ++i)
#pragma unroll
      for (int j = 0; j < 4; ++j)
        acc[i][j] = __builtin_amdgcn_mfma_f32_16x16x32_bf16(af[i], bfr[j], acc[i][j], 0, 0, 0);
  }
#pragma unroll
  for (int i = 0; i < 4; ++i)
#pragma unroll
    for (int j = 0; j < 4; ++j) {
      int col = n0 + wn * 64 + j * 16 + c;
#pragma unroll
      for (int reg = 0; reg < 4; ++reg) {
        int row = m0 + wm * 64 + i * 16 + q * 4 + reg;
        out[(size_t)row * 1024 + col] = acc[i][j][reg];
      }
    }
}

// ---------- vbuild: v combine into d-major vt, TRUE j order (32x32 flash
// consumes V[j][d] via B-frag k = contiguous j) ----------
__global__ __launch_bounds__(256) void vbuild_kernel(
    const uint16_t* __restrict__ proj, const uint4* __restrict__ gsel,
    uint16_t* __restrict__ vt)
{
  int bi = blockIdx.x;            // 1024 = bh(32) x tb(32)
  int bh = bi >> 5, tb = bi & 31;
  int b = bh >> 3, h = bh & 7;
  int t = threadIdx.x;
  int tt = t & 63, dg = t >> 6;
  int m = b * 2048 + tb * 64 + tt;
  uint4 gs = gsel[m * 8 + h];
  float w1 = __uint_as_float(gs.x), w2 = __uint_as_float(gs.y);
  int i1 = gs.z & 7, i2 = (gs.z >> 3) & 7;
  const uint16_t* base = proj + (size_t)m * PLD + 1024;
  const uint4* p1 = (const uint4*)(base + i1 * 64 + dg * 16);
  const uint4* p2 = (const uint4*)(base + i2 * 64 + dg * 16);
  uint4 A0 = p1[0], A1 = p1[1], B0 = p2[0], B1 = p2[1];
  float v[16];
  v[0]  = w1*bflo(A0.x) + w2*bflo(B0.x); v[1]  = w1*bfhi(A0.x) + w2*bfhi(B0.x);
  v[2]  = w1*bflo(A0.y) + w2*bflo(B0.y); v[3]  = w1*bfhi(A0.y) + w2*bfhi(B0.y);
  v[4]  = w1*bflo(A0.z) + w2*bflo(B0.z); v[5]  = w1*bfhi(A0.z) + w2*bfhi(B0.z);
  v[6]  = w1*bflo(A0.w) + w2*bflo(B0.w); v[7]  = w1*bfhi(A0.w) + w2*bfhi(B0.w);
  v[8]  = w1*bflo(A1.x) + w2*bflo(B1.x); v[9]  = w1*bfhi(A1.x) + w2*bfhi(B1.x);
  v[10] = w1*bflo(A1.y) + w2*bflo(B1.y); v[11] = w1*bfhi(A1.y) + w2*bfhi(B1.y);
  v[12] = w1*bflo(A1.z) + w2*bflo(B1.z); v[13] = w1*bfhi(A1.z) + w2*bfhi(B1.z);
  v[14] = w1*bflo(A1.w) + w2*bflo(B1.w); v[15] = w1*bfhi(A1.w) + w2*bfhi(B1.w);
#pragma unroll
  for (int dd = 0; dd < 16; ++dd)
    vt[(size_t)(bh * 64 + dg * 16 + dd) * 2048 + tb * 64 + tt] = bfr1(v[dd]);
}

// ---------- flash attention v3: 32x32x16 MFMA, swapped QK^T (S^T: q-row
// lane-local), in-register P via cvt_pk + permlane32_swap (T12), no Ps LDS,
// Q in regs, K/V register-prefetch, no-max softmax with folded 0.125 scale.
// Block = 128 q-rows x 4 waves (32 rows each); 32 KV-iterations of 64. ----------
__global__ __launch_bounds__(256) void flash_mfma_kernel(
    const uint16_t* __restrict__ proj, const uint16_t* __restrict__ vt,
    uint16_t* __restrict__ attnb)
{
  __shared__ __align__(16) uint16_t Ks[64 * 72];   // [j][d]
  __shared__ __align__(16) uint16_t Vs[64 * 72];   // [d][j] true-j order
  __shared__ float lsb[4 * 32];                    // per-wave 1/rowsum
  int t = threadIdx.x;
  int bx = blockIdx.x;
  int qb = bx & 15, bh = bx >> 4;
  int h = bh & 7, b = bh >> 3;
  int w = t >> 6, lane = t & 63;
  int r31 = lane & 31, hi = lane >> 5;
  int srow = t >> 2, scq = t & 3;

  // Q B-fragments (persist): B[k=d][n=r]: lane holds q-row r31 of this wave's
  // 32-row group, d = hi*8 + {0..7} + 16*f.
  short8 qf[4];
  {
    const uint16_t* qp = proj + (size_t)(b * 2048 + qb * 128 + w * 32 + r31) * PLD + h * 64 + hi * 8;
#pragma unroll
    for (int f = 0; f < 4; ++f) qf[f] = *(const short8*)(qp + 16 * f);
  }

  f32x16 o0 = {0.f}, o1 = {0.f};
#pragma unroll
  for (int i = 0; i < 16; ++i) { o0[i] = 0.f; o1[i] = 0.f; }
  float lsacc = 0.f;

  // K/V register prefetch: issue tile-it loads; LDS-write at top of it.
  const uint16_t* kg = proj + (size_t)(b * 2048 + srow) * PLD + 512 + h * 64 + scq * 16;
  const uint16_t* vg = vt + (size_t)(bh * 64 + srow) * 2048 + scq * 16;
  uint4 kp0, kp1, vp0, vp1;
  kp0 = ((const uint4*)kg)[0]; kp1 = ((const uint4*)kg)[1];
  vp0 = ((const uint4*)vg)[0]; vp1 = ((const uint4*)vg)[1];

  for (int it = 0; it < 32; ++it) {
    if (it) __syncthreads();             // prev compute done reading Ks/Vs
    *(uint4*)&Ks[srow * 72 + scq * 16] = kp0;
    *(uint4*)&Ks[srow * 72 + scq * 16 + 8] = kp1;
    *(uint4*)&Vs[srow * 72 + scq * 16] = vp0;
    *(uint4*)&Vs[srow * 72 + scq * 16 + 8] = vp1;
    __syncthreads();
    if (it < 31) {                       // overlap next-tile loads with compute
      const uint4* pk = (const uint4*)(kg + (size_t)(it + 1) * 64 * PLD);
      kp0 = pk[0]; kp1 = pk[1];
      const uint4* pv = (const uint4*)(vg + (it + 1) * 64);
      vp0 = pv[0]; vp1 = pv[1];
    }

    // Per j-group (32 K-rows): S^T = mfma(A=K, B=Q); C col = r (lane-local
    // q-row), C row j = (reg&3) + 8*(reg>>2) + 4*hi. Then P in-register.
    short8 pa[4];
#pragma unroll
    for (int jg = 0; jg < 2; ++jg) {
      f32x16 s;
#pragma unroll
      for (int i = 0; i < 16; ++i) s[i] = 0.f;
#pragma unroll
      for (int f = 0; f < 4; ++f) {
        short8 kf = *(const short8*)&Ks[(jg * 32 + r31) * 72 + hi * 8 + 16 * f];
        s = __builtin_amdgcn_mfma_f32_32x32x16_bf16(kf, qf[f], s, 0, 0, 0);
      }
      float p[16];
#pragma unroll
      for (int reg = 0; reg < 16; ++reg)
        p[reg] = __builtin_amdgcn_exp2f(s[reg] * 0.18033688f);
      lsacc += (((p[0] + p[1]) + (p[2] + p[3])) + ((p[4] + p[5]) + (p[6] + p[7])))
             + (((p[8] + p[9]) + (p[10] + p[11])) + ((p[12] + p[13]) + (p[14] + p[15])));
      // cvt_pk adjacent-j pairs, then permlane32_swap to assemble PV A-frags
      uint32_t X1 = cvtpk(p[0], p[1]),  X2 = cvtpk(p[2], p[3]);
      uint32_t Y1 = cvtpk(p[4], p[5]),  Y2 = cvtpk(p[6], p[7]);
      uint32_t Z1 = cvtpk(p[8], p[9]),  Z2 = cvtpk(p[10], p[11]);
      uint32_t W1 = cvtpk(p[12], p[13]), W2 = cvtpk(p[14], p[15]);
      u32x2 s1 = __builtin_amdgcn_permlane32_swap(X1, Y1, false, false);
      u32x2 s2 = __builtin_amdgcn_permlane32_swap(X2, Y2, false, false);
      u32x2 s3 = __builtin_amdgcn_permlane32_swap(Z1, W1, false, false);
      u32x2 s4 = __builtin_amdgcn_permlane32_swap(Z2, W2, false, false);
      uint4 f0 = { s1.x, s2.x, s1.y, s2.y };   // j = jg*32 + hi*8 + 0..7
      uint4 f1 = { s3.x, s4.x, s3.y, s4.y };   // j = jg*32 + 16 + hi*8 + 0..7
      pa[jg * 2 + 0] = *(short8*)&f0;
      pa[jg * 2 + 1] = *(short8*)&f1;
    }

    // O += P V : per d-tile, 4 mfma over j=64; B=V from d-major Vs (true j).
#pragma unroll
    for (int f = 0; f < 4; ++f) {
      short8 vf0 = *(const short8*)&Vs[(r31) * 72 + hi * 8 + 16 * f];
      short8 vf1 = *(const short8*)&Vs[(32 + r31) * 72 + hi * 8 + 16 * f];
      o0 = __builtin_amdgcn_mfma_f32_32x32x16_bf16(pa[f], vf0, o0, 0, 0, 0);
      o1 = __builtin_amdgcn_mfma_f32_32x32x16_bf16(pa[f], vf1, o1, 0, 0, 0);
    }
  }

  // row sums: lane-local partial + partner half; broadcast 1/ls via wave-
  // private LDS (same-wave DS ordering, no barrier needed).
  float lsc = lsacc + __shfl_xor(lsacc, 32);
  if (lane < 32) lsb[w * 32 + r31] = 1.0f / lsc;
#pragma unroll
  for (int reg = 0; reg < 16; ++reg) {
    int r = (reg & 3) + 8 * (reg >> 2) + 4 * hi;
    float inv = lsb[w * 32 + r];
    size_t row = (size_t)(b * 2048 + qb * 128 + w * 32 + r);
    attnb[row * 512 + h * 64 + r31]      = bfr1(o0[reg] * inv);
    attnb[row * 512 + h * 64 + 32 + r31] = bfr1(o1[reg] * inv);
  }
}

// ---------- zbuild: z[m][e*64+c] = sum_h mask_o[h,e] * attn[m][h*64+c] ----------
__global__ __launch_bounds__(64) void zbuild_kernel(
    const uint16_t* __restrict__ attnb, const uint32_t* __restrict__ gselw,
    uint16_t* __restrict__ zbuf)
{
  int m = blockIdx.x; int c = threadIdx.x;
  float acc[5] = {0.f, 0.f, 0.f, 0.f, 0.f};
#pragma unroll
  for (int h = 0; h < 8; ++h) {
    uint32_t sel = gselw[(m * 8 + h) * 4 + 3];
    int e1 = sel & 7, e2 = (sel >> 3) & 7;
    float a = bf2f(attnb[(size_t)m * 512 + h * 64 + c]);
#pragma unroll
    for (int e = 0; e < 5; ++e)
      acc[e] += (e == e1 || e == e2) ? a : 0.f;
  }
#pragma unroll
  for (int e = 0; e < 5; ++e)
    zbuf[(size_t)m * 320 + e * 64 + c] = bfr1(acc[e]);
}

// ---------- launch ----------
extern "C" void kernel_launch(void* const* d_in, const int* in_sizes, int n_in,
                              void* d_out, int out_size, void* d_ws, size_t ws_size,
                              hipStream_t stream) {
  const float* x  = (const float*)d_in[0];
  const float* Wq = (const float*)d_in[1];
  const float* Wk = (const float*)d_in[2];
  const float* Ws = (const float*)d_in[3];
  const float* Wd = (const float*)d_in[4];
  const float* Wv = (const float*)d_in[5];
  const float* Wo = (const float*)d_in[6];
  float* out = (float*)d_out;

  // workspace carve, lifetime-aliased; high-water 51,773,440 B
  char* ws = (char*)d_ws;
  uint4*    gsel  = (uint4*)   (ws);                  // [0, 1,048,576)
  uint16_t* WoT   = (uint16_t*)(ws + 1048576);        // [.., 1,703,936)
  uint16_t* Wt    = (uint16_t*)(ws + 1703936);        // [.., 4,587,520)  dead after proj
  uint16_t* xb    = (uint16_t*)(ws + 4587520);        // [.., 21,364,736) dead after proj
  uint16_t* proj  = (uint16_t*)(ws + 21364736);       // [.., 43,384,832)
  uint16_t* vt    = (uint16_t*)(ws + 43384832);       // [.., 51,773,440)
  uint16_t* attnb = (uint16_t*)(ws + 1703936);        // alias Wt+xb (dead)
  uint16_t* zbuf  = (uint16_t*)(ws + 10092544);       // alias xb tail

  gate_v6_kernel<<<dim3(MM / 64, 2), 1024, 0, stream>>>(x, Ws, Wd, (uint32_t*)gsel);
  pack_wt_kernel<<<dim3(16, 22), 256, 0, stream>>>(Wq, Wk, Wv, Wt);
  pack_wot_kernel<<<dim3(5, 16), 256, 0, stream>>>(Wo, WoT);
  xbf_kernel<<<(MM * DD / 4) / 256, 256, 0, stream>>>(x, xb);
  proj_mfma_kernel<<<dim3(NWT / 128, MM / 128), 256, 0, stream>>>(xb, Wt, proj);
  vbuild_kernel<<<32 * 32, 256, 0, stream>>>(proj, gsel, vt);
  flash_mfma_kernel<<<BB * HH * (TT / 128), 256, 0, stream>>>(proj, vt, attnb);
  zbuild_kernel<<<MM, 64, 0, stream>>>(attnb, (const uint32_t*)gsel, zbuf);
  out_mfma_kernel<<<dim3(DD / 128, MM / 128), 256, 0, stream>>>(zbuf, WoT, out);
}